// Round 7
// baseline (16693.394 us; speedup 1.0000x reference)
//
#include <hip/hip_runtime.h>
#include <cstdint>

#define TT 128   // time steps (= bucket_size)
#define BB 128   // batch
#define II 512   // input dim
#define HH 512   // hidden dim
#define DD 1024  // I + H
#define NC 513   // H + 1
#define NPAD 520 // row pitch for lnXW / vbuf (bf16)
#define NT 36    // n-tiles of 16 in big GEMM (576 padded cols)
#define EPSL 1e-5f

typedef short    s8v  __attribute__((ext_vector_type(8)));
typedef float    f4v  __attribute__((ext_vector_type(4)));
typedef _Float16 h2v  __attribute__((ext_vector_type(2)));

__device__ __forceinline__ ushort f2bf(float f){
  uint u = __builtin_bit_cast(uint, f);
  uint r = (u + 0x7fffu + ((u >> 16) & 1u)) >> 16;
  return (ushort)r;
}
__device__ __forceinline__ float bf2f(ushort s){
  uint u = ((uint)s) << 16;
  return __builtin_bit_cast(float, u);
}
__device__ __forceinline__ float hsig(float x){
  return fminf(fmaxf(0.2f * x + 0.5f, 0.f), 1.f);
}
// fast tanh via exp2; |err| ~1e-6
__device__ __forceinline__ float ftanh(float x){
  float ax = fminf(fabsf(x), 15.f);
  float e  = __builtin_amdgcn_exp2f(ax * 2.885390082f);   // 2*log2(e)
  float r  = (e - 1.f) * __builtin_amdgcn_rcpf(e + 1.f);
  return __builtin_copysignf(r, x);
}
// f32 += dot(f16x2, f16x2) — exact products, f32 accumulate
__device__ __forceinline__ float dot2(uint a, uint b, float c){
#if __has_builtin(__builtin_amdgcn_fdot2)
  return __builtin_amdgcn_fdot2(__builtin_bit_cast(h2v, a),
                                __builtin_bit_cast(h2v, b), c, false);
#else
  h2v x = __builtin_bit_cast(h2v, a), y = __builtin_bit_cast(h2v, b);
  return fmaf((float)x[1], (float)y[1], fmaf((float)x[0], (float)y[0], c));
#endif
}

// ---------------- pre-pack W / U into MFMA B-fragment order (bf16, big GEMM) ----
__global__ void prepack_B(const float* __restrict__ src, ushort* __restrict__ dst){
  int idx = blockIdx.x * 256 + threadIdx.x;
  if (idx >= 128 * NT * 16 * 8) return;
  int kl = idx & 7;
  int ni = (idx >> 3) & 15;
  int nt = (idx >> 7) % NT;
  int kc = idx / (NT * 16 * 8);
  int k = kc * 8 + kl;
  int n = nt * 16 + ni;
  float v = (n < NC) ? src[k * NC + n] : 0.f;
  dst[idx] = f2bf(v);
}

// ---------------- pre-pack U_hi (rows II..II+511) as f16 pairs for fdot2 --------
// uint idx = (c*512 + n)*4 + j holds f16 pair (U[II+8c+2j][n], U[II+8c+2j+1][n]).
__global__ void prepack_Uhi_pk(const float* __restrict__ U, uint* __restrict__ dst,
                               float* __restrict__ ucol){
  int idx = blockIdx.x * 256 + threadIdx.x;
  if (idx < 64 * 512 * 4){
    int j = idx & 3;
    int n = (idx >> 2) & 511;
    int c = idx >> 11;
    int k0 = II + 8 * c + 2 * j;
    _Float16 lo = (_Float16)U[(size_t)k0 * NC + n];
    _Float16 hi = (_Float16)U[(size_t)(k0 + 1) * NC + n];
    dst[idx] = (uint)__builtin_bit_cast(ushort, lo)
             | ((uint)__builtin_bit_cast(ushort, hi) << 16);
  }
  if (idx < 512) ucol[idx] = U[(size_t)(II + idx) * NC + 512];
}

// ---------------- fused GEMM (+ optional row-LayerNorm) -------------------
__global__ __launch_bounds__(1024) void gemm_ln(
    const float* __restrict__ A, int amode, int ksteps,
    const ushort* __restrict__ Bpk, ushort* __restrict__ out,
    int do_ln, const float* __restrict__ gam, const float* __restrict__ bet,
    const float* __restrict__ bias)
{
  __shared__ ushort As[64][40];
  __shared__ float red[4][4][16][2];
  int tid = threadIdx.x;
  int lane = tid & 63, wid = tid >> 6;
  int quad = lane >> 4, l16 = lane & 15;
  int wm = wid >> 2, wn = wid & 3;
  int blk = blockIdx.x;

  f4v acc[9];
#pragma unroll
  for (int i = 0; i < 9; i++) acc[i] = (f4v){0.f, 0.f, 0.f, 0.f};

  int arow = tid >> 4;
  int acp  = tid & 15;
  int r = blk * 64 + arow;
  const float* aptr;
  if (amode == 0){ int t = r >> 7, b = r & 127; aptr = A + ((size_t)(b * TT + t)) * II + acp * 2; }
  else           { aptr = A + (size_t)r * DD + acp * 2; }

  for (int ks = 0; ks < ksteps; ks++){
    __syncthreads();
    float2 a2 = *(const float2*)(aptr + ks * 32);
    uint pk = (uint)f2bf(a2.x) | ((uint)f2bf(a2.y) << 16);
    *(uint*)&As[arow][acp * 2] = pk;
    __syncthreads();
    s8v af = *(const s8v*)&As[wm * 16 + l16][quad * 8];
    int kc = ks * 4 + quad;
    const s8v* bp = (const s8v*)Bpk + (size_t)kc * (NT * 16) + l16;
#pragma unroll
    for (int i = 0; i < 9; i++){
      s8v bf = bp[(wn * 9 + i) * 16];
      acc[i] = __builtin_amdgcn_mfma_f32_16x16x32_bf16(af, bf, acc[i], 0, 0, 0);
    }
  }

  int rowbase = blk * 64 + wm * 16 + quad * 4;
  if (do_ln){
    float s1[4], s2[4];
#pragma unroll
    for (int g = 0; g < 4; g++){
      float a = 0.f, q = 0.f;
#pragma unroll
      for (int i = 0; i < 9; i++){ float v = acc[i][g]; a += v; q += v * v; }
#pragma unroll
      for (int m = 1; m < 16; m <<= 1){ a += __shfl_xor(a, m, 64); q += __shfl_xor(q, m, 64); }
      s1[g] = a; s2[g] = q;
    }
    if (l16 == 0){
#pragma unroll
      for (int g = 0; g < 4; g++){
        red[wm][wn][quad * 4 + g][0] = s1[g];
        red[wm][wn][quad * 4 + g][1] = s2[g];
      }
    }
    __syncthreads();
#pragma unroll
    for (int g = 0; g < 4; g++){
      int rr = quad * 4 + g;
      float S1 = red[wm][0][rr][0] + red[wm][1][rr][0] + red[wm][2][rr][0] + red[wm][3][rr][0];
      float S2 = red[wm][0][rr][1] + red[wm][1][rr][1] + red[wm][2][rr][1] + red[wm][3][rr][1];
      float mean = S1 * (1.f / 513.f);
      float var  = S2 * (1.f / 513.f) - mean * mean;
      float inv  = 1.f / (sqrtf(var + EPSL) + EPSL);
      size_t rg = (size_t)(rowbase + g);
#pragma unroll
      for (int i = 0; i < 9; i++){
        int n = wn * 144 + i * 16 + l16;
        if (n < NC){
          float val = gam[n] * ((acc[i][g] - mean) * inv) + bet[n] + bias[n];
          out[rg * NPAD + n] = f2bf(val);
        }
      }
    }
  } else {
#pragma unroll
    for (int g = 0; g < 4; g++){
      size_t rg = (size_t)(rowbase + g);
#pragma unroll
      for (int i = 0; i < 9; i++){
        int n = wn * 144 + i * 16 + l16;
        if (n < NC) out[rg * NPAD + n] = f2bf(acc[i][g]);
      }
    }
  }
}

// ---------------- per-batch-row sequential recurrence (intra-block only) ----
// one block per batch row; 512 threads = 8 waves; thread n owns column n.
// 2 barriers per step. GEMV via v_dot2_f32_f16, FULLY UNROLLED with a 256-VGPR
// budget (__launch_bounds__(512,2)) so ~16-24 U loads stay in flight — r5/r6
// showed the 64-VGPR allocation serialized the L2 loads (the dominant stall).
__global__ __launch_bounds__(512, 2) void rnn_layer(
    int layer,
    const float* __restrict__ x,
    float* __restrict__ h_seq,
    const ushort* __restrict__ lnXW,
    ushort* __restrict__ vbuf,
    float* __restrict__ fkbuf,
    float* __restrict__ hvbuf,
    const uint* __restrict__ Upk4,
    const float* __restrict__ ucol,
    const int* __restrict__ mask,
    const float* __restrict__ gam1, const float* __restrict__ bet1,
    const float* __restrict__ bias,
    float* __restrict__ out)
{
  __shared__ __align__(16) ushort tanh16[512];  // f16 tanh (GEMV operand, pair-packed)
  __shared__ __align__(16) float  tanhvf[512];  // f32 tanh (h update / col-512 dot)
  __shared__ float red_a[8], red_q[8], red_p[8];
  __shared__ float sh_v0;
  __shared__ int msk[TT];

  int tid = threadIdx.x;
  int b = blockIdx.x;
  int lane = tid & 63, wid = tid >> 6;
  const bool lastL = (layer == 3);

  float sv = 0.f;                    // own v column
  float v512 = 0.f;                  // uniform on all threads
  float h_lo = 0.f, h_hi = 0.f;
  float fkc = 0.f, hvc = 0.f;        // uniform gate carries
  float g1n = gam1[tid], b1n = bet1[tid];
  float g10 = gam1[0],  b10 = bet1[0];
  float g1e = gam1[512], b1e = bet1[512];
  float bias0 = bias[0];
  float uc = ucol[tid];
  // previous-step gates for the deferred (uniform) col-512 update
  float ho_p = 0.f, xo_p = 0.f, bo_p = 0.f, xu5_p = 0.f;
  int mk_p = 0;

  if (tid < TT) msk[tid] = mask[b * TT + tid];
  if (lane == 0){ red_a[wid] = 0.f; red_q[wid] = 0.f; red_p[wid] = 0.f; }
  if (tid == 0) sh_v0 = 0.f;
  __syncthreads();

  for (int t = 0; t < TT; t++){
    size_t row = (size_t)(t * BB + b);

    // ---- P0: issue this step's loads
    float lw    = bf2f(lnXW[row * NPAD + tid]);
    float lw0   = bf2f(lnXW[row * NPAD]);
    float lw512 = bf2f(lnXW[row * NPAD + 512]);
    float xu    = bf2f(vbuf[row * NPAD + tid]);
    float xu5   = bf2f(vbuf[row * NPAD + 512]);      // broadcast (uniform)
    float xlo, xhi;
    if (layer == 0){ xlo = x[((size_t)(b * TT + t)) * II + tid]; xhi = 0.f; }
    else { xlo = h_seq[row * DD + tid]; xhi = h_seq[row * DD + 512 + tid]; }
    float fkp_tm1 = 0.f, fkp = 0.f, hvp = 1.f;
    if (layer > 0){
      fkp_tm1 = fkbuf[t * BB + b];
      fkp = (t + 1 < TT) ? fkbuf[(t + 1) * BB + b] : 0.f;
      hvp = hvbuf[t * BB + b];
    }
    int mraw  = msk[t];
    int mprev = (t > 0) ? msk[t - 1] : 0;

    // ---- P1: uniform col-512 update (prev step), LN stats, gates (all threads)
    if (t > 0){
      float y512 = red_p[0] + red_p[1] + red_p[2] + red_p[3]
                 + red_p[4] + red_p[5] + red_p[6] + red_p[7];
      float nv5 = ho_p * v512 + xo_p * xu5_p + bo_p * y512;
      if (mk_p) v512 = nv5;
      if (tid == 0 && !lastL) vbuf[(row - BB) * NPAD + 512] = f2bf(v512);
    }
    float S = red_a[0] + red_a[1] + red_a[2] + red_a[3]
            + red_a[4] + red_a[5] + red_a[6] + red_a[7];
    float Q = red_q[0] + red_q[1] + red_q[2] + red_q[3]
            + red_q[4] + red_q[5] + red_q[6] + red_q[7];
    S += v512; Q += v512 * v512;
    float v0 = sh_v0;
    float mean = S * (1.f / 513.f);
    float var  = Q * (1.f / 513.f) - mean * mean;
    float inv  = 1.f / (sqrtf(var + EPSL) + EPSL);

    bool mk  = mraw > 0;
    bool mk2 = (t > 0) && (mprev > 0) && !mk;
    float sum20 = (v0 - mean) * inv * g10 + b10;
    float s0 = lw0 + sum20;
    float fk_both = hsig(s0);
    float fk_t1   = hsig(sum20 + bias0);
    float fk = fkp_tm1 + (1.f - fkp_tm1) * (fkc * fk_both + (1.f - fkc) * fk_t1);
    if (mk2) fk = 0.f;
    float h_only = hvc * fk * (fkp + (1.f - fkp) * (1.f - hvp));
    float x_only = hvp * (1.f - fkp) * (1.f - fk + fk * (1.f - hvc));
    float both   = (1.f - fkp) * fk * hvc * hvp;
    float hv = 1.f - (1.f - h_only) * (1.f - x_only) * (1.f - both);
    fkc = mk ? fk : fkc;
    hvc = mk ? hv : hvc;
    if (mk2) fkc = 0.f;

    // ---- P2: LN apply + tanh; stage f16 (pair-packed via layout) and f32
    {
      float sum2 = (sv - mean) * inv * g1n + b1n;
      float s = lw + sum2;
      float th = ftanh(s);
      if (tid == 0){
        float sum2e = (v512 - mean) * inv * g1e + b1e;
        float the = ftanh(lw512 + sum2e);
        tanh16[511] = __builtin_bit_cast(ushort, (_Float16)the);
        tanhvf[511] = the;
      } else {
        tanh16[tid - 1] = __builtin_bit_cast(ushort, (_Float16)th);
        tanhvf[tid - 1] = th;
      }
    }
    __syncthreads();   // B1: tanh staged

    // ---- P3: GEMV y[n] = sum_k tanh[k] * U_hi[k][n] via fdot2 (full unroll,
    //          deep load pipeline — needs the 256-VGPR budget)
    float y0 = 0.f, y1 = 0.f, y2 = 0.f, y3 = 0.f;
    {
      const uint4* up = (const uint4*)Upk4 + tid;
      const uint4* tp = (const uint4*)tanh16;
#pragma unroll
      for (int c = 0; c < 64; c++){
        uint4 uu = up[(size_t)c * 512];   // coalesced 16B / lane (L2 resident)
        uint4 tt = tp[c];                 // LDS broadcast
        y0 = dot2(tt.x, uu.x, y0);
        y1 = dot2(tt.y, uu.y, y1);
        y2 = dot2(tt.z, uu.z, y2);
        y3 = dot2(tt.w, uu.w, y3);
      }
    }
    float y = (y0 + y1) + (y2 + y3);
    // col-512 partial: this thread's tanh (core col tid) x U[II+tid][512]
    {
      float p = tanhvf[tid] * uc;
#pragma unroll
      for (int m = 1; m < 64; m <<= 1) p += __shfl_xor(p, m, 64);
      if (lane == 0) red_p[wid] = p;     // read next step (after step-start barrier)
    }

    // ---- P4: state updates, stream writes, next-step LN stats
    float nv = h_only * sv + x_only * xu + both * y;
    if (mk) sv = nv;
    float thh = tanhvf[tid];
    float nh_lo = h_only * h_lo + x_only * xlo;
    float nh_hi = h_only * h_hi + x_only * xhi + both * thh;
    if (mk){ h_lo = nh_lo; h_hi = nh_hi; }
    if (!lastL){
      vbuf[row * NPAD + tid] = f2bf(sv);
      h_seq[row * DD + tid] = h_lo;
      h_seq[row * DD + 512 + tid] = h_hi;
      if (tid == 0){ fkbuf[t * BB + b] = fkc; hvbuf[t * BB + b] = hvc; }
    }
    if (lastL && t == TT - 1) out[b * HH + tid] = h_hi;

    ho_p = h_only; xo_p = x_only; bo_p = both; mk_p = mk ? 1 : 0; xu5_p = xu5;

    {
      float a = sv, q = sv * sv;
#pragma unroll
      for (int m = 1; m < 64; m <<= 1){ a += __shfl_xor(a, m, 64); q += __shfl_xor(q, m, 64); }
      if (lane == 0){ red_a[wid] = a; red_q[wid] = q; }
      if (tid == 0) sh_v0 = sv;
    }
    __syncthreads();   // B2 (= next step's start barrier)
  }

  // epilogue: final col-512 update (t = TT-1)
  if (tid == 0 && !lastL){
    float y512 = red_p[0] + red_p[1] + red_p[2] + red_p[3]
               + red_p[4] + red_p[5] + red_p[6] + red_p[7];
    float nv5 = ho_p * v512 + xo_p * xu5_p + bo_p * y512;
    if (mk_p) v512 = nv5;
    vbuf[(size_t)((TT - 1) * BB + b) * NPAD + 512] = f2bf(v512);
  }
}

extern "C" void kernel_launch(void* const* d_in, const int* in_sizes, int n_in,
                              void* d_out, int out_size, void* d_ws, size_t ws_size,
                              hipStream_t stream)
{
  (void)in_sizes; (void)n_in; (void)out_size; (void)ws_size;
  const float* x      = (const float*)d_in[0];
  const int*   mask   = (const int*)d_in[1];
  const float* W      = (const float*)d_in[2];
  const float* U      = (const float*)d_in[3];
  const float* bias   = (const float*)d_in[4];
  const float* gammas = (const float*)d_in[5];
  const float* betas  = (const float*)d_in[6];
  float* out = (float*)d_out;

  char* ws = (char*)d_ws;
  size_t off = 0;
  auto alloc = [&](size_t bytes) -> void* {
    void* p = ws + off;
    off += (bytes + 255) & ~(size_t)255;
    return p;
  };
  float*  h_seq = (float*) alloc((size_t)TT * BB * DD * 4);
  ushort* lnXW  = (ushort*)alloc((size_t)TT * BB * NPAD * 2);
  ushort* vbuf  = (ushort*)alloc((size_t)TT * BB * NPAD * 2);
  float*  fkbuf = (float*) alloc((size_t)TT * BB * 4);
  float*  hvbuf = (float*) alloc((size_t)TT * BB * 4);
  ushort* Wpk   = (ushort*)alloc((size_t)128 * NT * 16 * 8 * 2);
  ushort* Upk   = (ushort*)alloc((size_t)128 * NT * 16 * 8 * 2);
  uint*   Upk4  = (uint*)  alloc((size_t)64 * 512 * 4 * 4);
  float*  ucol  = (float*) alloc(512 * 4);

  int npk = 128 * NT * 16 * 8;
  prepack_B<<<dim3((npk + 255) / 256), dim3(256), 0, stream>>>(W, Wpk);
  prepack_B<<<dim3((npk + 255) / 256), dim3(256), 0, stream>>>(U, Upk);
  prepack_Uhi_pk<<<dim3((64 * 512 * 4 + 255) / 256), dim3(256), 0, stream>>>(U, Upk4, ucol);

  const float* g0 = gammas,      *g1 = gammas + NC;
  const float* be0 = betas,      *be1 = betas + NC;

  // layer 0: lnXW = LN(x @ W_lo)+b ; vbuf = x @ U_lo (raw)
  gemm_ln<<<dim3(256), dim3(1024), 0, stream>>>(x, 0, 16, Wpk, lnXW, 1, g0, be0, bias);
  gemm_ln<<<dim3(256), dim3(1024), 0, stream>>>(x, 0, 16, Upk, vbuf, 0, g0, be0, bias);
  rnn_layer<<<dim3(BB), dim3(512), 0, stream>>>(0, x, h_seq, lnXW, vbuf, fkbuf, hvbuf,
                                                Upk4, ucol, mask, g1, be1, bias, out);
  for (int d = 1; d < 4; d++){
    gemm_ln<<<dim3(256), dim3(1024), 0, stream>>>(h_seq, 1, 32, Wpk, lnXW, 1, g0, be0, bias);
    rnn_layer<<<dim3(BB), dim3(512), 0, stream>>>(d, x, h_seq, lnXW, vbuf, fkbuf, hvbuf,
                                                  Upk4, ucol, mask, g1, be1, bias, out);
  }
}

// Round 8
// 16326.926 us; speedup vs baseline: 1.0224x; 1.0224x over previous
//
#include <hip/hip_runtime.h>
#include <cstdint>

#define TT 128   // time steps (= bucket_size)
#define BB 128   // batch
#define II 512   // input dim
#define HH 512   // hidden dim
#define DD 1024  // I + H
#define NC 513   // H + 1
#define NPAD 520 // row pitch for lnXW / vbuf (bf16)
#define NT 36    // n-tiles of 16 in big GEMM (576 padded cols)
#define EPSL 1e-5f

typedef short    s8v  __attribute__((ext_vector_type(8)));
typedef float    f4v  __attribute__((ext_vector_type(4)));
typedef _Float16 h2v  __attribute__((ext_vector_type(2)));

__device__ __forceinline__ ushort f2bf(float f){
  uint u = __builtin_bit_cast(uint, f);
  uint r = (u + 0x7fffu + ((u >> 16) & 1u)) >> 16;
  return (ushort)r;
}
__device__ __forceinline__ float bf2f(ushort s){
  uint u = ((uint)s) << 16;
  return __builtin_bit_cast(float, u);
}
__device__ __forceinline__ float hsig(float x){
  return fminf(fmaxf(0.2f * x + 0.5f, 0.f), 1.f);
}
// fast tanh via exp2; |err| ~1e-6
__device__ __forceinline__ float ftanh(float x){
  float ax = fminf(fabsf(x), 15.f);
  float e  = __builtin_amdgcn_exp2f(ax * 2.885390082f);   // 2*log2(e)
  float r  = (e - 1.f) * __builtin_amdgcn_rcpf(e + 1.f);
  return __builtin_copysignf(r, x);
}
// f32 += dot(f16x2, f16x2) — exact products, f32 accumulate
__device__ __forceinline__ float dot2(uint a, uint b, float c){
#if __has_builtin(__builtin_amdgcn_fdot2)
  return __builtin_amdgcn_fdot2(__builtin_bit_cast(h2v, a),
                                __builtin_bit_cast(h2v, b), c, false);
#else
  h2v x = __builtin_bit_cast(h2v, a), y = __builtin_bit_cast(h2v, b);
  return fmaf((float)x[1], (float)y[1], fmaf((float)x[0], (float)y[0], c));
#endif
}

// ---------------- pre-pack W / U into MFMA B-fragment order (bf16, big GEMM) ----
__global__ void prepack_B(const float* __restrict__ src, ushort* __restrict__ dst){
  int idx = blockIdx.x * 256 + threadIdx.x;
  if (idx >= 128 * NT * 16 * 8) return;
  int kl = idx & 7;
  int ni = (idx >> 3) & 15;
  int nt = (idx >> 7) % NT;
  int kc = idx / (NT * 16 * 8);
  int k = kc * 8 + kl;
  int n = nt * 16 + ni;
  float v = (n < NC) ? src[k * NC + n] : 0.f;
  dst[idx] = f2bf(v);
}

// ---------------- pre-pack U_hi (rows II..II+511) as f16 pairs for fdot2 --------
// uint idx = (c*512 + n)*4 + j holds f16 pair (U[II+8c+2j][n], U[II+8c+2j+1][n]).
__global__ void prepack_Uhi_pk(const float* __restrict__ U, uint* __restrict__ dst,
                               float* __restrict__ ucol){
  int idx = blockIdx.x * 256 + threadIdx.x;
  if (idx < 64 * 512 * 4){
    int j = idx & 3;
    int n = (idx >> 2) & 511;
    int c = idx >> 11;
    int k0 = II + 8 * c + 2 * j;
    _Float16 lo = (_Float16)U[(size_t)k0 * NC + n];
    _Float16 hi = (_Float16)U[(size_t)(k0 + 1) * NC + n];
    dst[idx] = (uint)__builtin_bit_cast(ushort, lo)
             | ((uint)__builtin_bit_cast(ushort, hi) << 16);
  }
  if (idx < 512) ucol[idx] = U[(size_t)(II + idx) * NC + 512];
}

// ---------------- fused GEMM (+ optional row-LayerNorm) -------------------
__global__ __launch_bounds__(1024) void gemm_ln(
    const float* __restrict__ A, int amode, int ksteps,
    const ushort* __restrict__ Bpk, ushort* __restrict__ out,
    int do_ln, const float* __restrict__ gam, const float* __restrict__ bet,
    const float* __restrict__ bias)
{
  __shared__ ushort As[64][40];
  __shared__ float red[4][4][16][2];
  int tid = threadIdx.x;
  int lane = tid & 63, wid = tid >> 6;
  int quad = lane >> 4, l16 = lane & 15;
  int wm = wid >> 2, wn = wid & 3;
  int blk = blockIdx.x;

  f4v acc[9];
#pragma unroll
  for (int i = 0; i < 9; i++) acc[i] = (f4v){0.f, 0.f, 0.f, 0.f};

  int arow = tid >> 4;
  int acp  = tid & 15;
  int r = blk * 64 + arow;
  const float* aptr;
  if (amode == 0){ int t = r >> 7, b = r & 127; aptr = A + ((size_t)(b * TT + t)) * II + acp * 2; }
  else           { aptr = A + (size_t)r * DD + acp * 2; }

  for (int ks = 0; ks < ksteps; ks++){
    __syncthreads();
    float2 a2 = *(const float2*)(aptr + ks * 32);
    uint pk = (uint)f2bf(a2.x) | ((uint)f2bf(a2.y) << 16);
    *(uint*)&As[arow][acp * 2] = pk;
    __syncthreads();
    s8v af = *(const s8v*)&As[wm * 16 + l16][quad * 8];
    int kc = ks * 4 + quad;
    const s8v* bp = (const s8v*)Bpk + (size_t)kc * (NT * 16) + l16;
#pragma unroll
    for (int i = 0; i < 9; i++){
      s8v bf = bp[(wn * 9 + i) * 16];
      acc[i] = __builtin_amdgcn_mfma_f32_16x16x32_bf16(af, bf, acc[i], 0, 0, 0);
    }
  }

  int rowbase = blk * 64 + wm * 16 + quad * 4;
  if (do_ln){
    float s1[4], s2[4];
#pragma unroll
    for (int g = 0; g < 4; g++){
      float a = 0.f, q = 0.f;
#pragma unroll
      for (int i = 0; i < 9; i++){ float v = acc[i][g]; a += v; q += v * v; }
#pragma unroll
      for (int m = 1; m < 16; m <<= 1){ a += __shfl_xor(a, m, 64); q += __shfl_xor(q, m, 64); }
      s1[g] = a; s2[g] = q;
    }
    if (l16 == 0){
#pragma unroll
      for (int g = 0; g < 4; g++){
        red[wm][wn][quad * 4 + g][0] = s1[g];
        red[wm][wn][quad * 4 + g][1] = s2[g];
      }
    }
    __syncthreads();
#pragma unroll
    for (int g = 0; g < 4; g++){
      int rr = quad * 4 + g;
      float S1 = red[wm][0][rr][0] + red[wm][1][rr][0] + red[wm][2][rr][0] + red[wm][3][rr][0];
      float S2 = red[wm][0][rr][1] + red[wm][1][rr][1] + red[wm][2][rr][1] + red[wm][3][rr][1];
      float mean = S1 * (1.f / 513.f);
      float var  = S2 * (1.f / 513.f) - mean * mean;
      float inv  = 1.f / (sqrtf(var + EPSL) + EPSL);
      size_t rg = (size_t)(rowbase + g);
#pragma unroll
      for (int i = 0; i < 9; i++){
        int n = wn * 144 + i * 16 + l16;
        if (n < NC){
          float val = gam[n] * ((acc[i][g] - mean) * inv) + bet[n] + bias[n];
          out[rg * NPAD + n] = f2bf(val);
        }
      }
    }
  } else {
#pragma unroll
    for (int g = 0; g < 4; g++){
      size_t rg = (size_t)(rowbase + g);
#pragma unroll
      for (int i = 0; i < 9; i++){
        int n = wn * 144 + i * 16 + l16;
        if (n < NC) out[rg * NPAD + n] = f2bf(acc[i][g]);
      }
    }
  }
}

// 8-wide register-bank load / consume macros for the pipelined GEMV.
// base is a compile-time constant in every expansion (unrolled context).
#define LD8(r0,r1,r2,r3,r4,r5,r6,r7,base) do{                 \
  r0 = up[(size_t)((base)+0) * 512];                          \
  r1 = up[(size_t)((base)+1) * 512];                          \
  r2 = up[(size_t)((base)+2) * 512];                          \
  r3 = up[(size_t)((base)+3) * 512];                          \
  r4 = up[(size_t)((base)+4) * 512];                          \
  r5 = up[(size_t)((base)+5) * 512];                          \
  r6 = up[(size_t)((base)+6) * 512];                          \
  r7 = up[(size_t)((base)+7) * 512];                          \
}while(0)

#define CO1(r,c) do{ uint4 t_ = tp[(c)];                      \
  y0 = dot2(t_.x, r.x, y0); y1 = dot2(t_.y, r.y, y1);         \
  y2 = dot2(t_.z, r.z, y2); y3 = dot2(t_.w, r.w, y3); }while(0)

#define CO8(r0,r1,r2,r3,r4,r5,r6,r7,base) do{                 \
  CO1(r0,(base)+0); CO1(r1,(base)+1); CO1(r2,(base)+2);       \
  CO1(r3,(base)+3); CO1(r4,(base)+4); CO1(r5,(base)+5);       \
  CO1(r6,(base)+6); CO1(r7,(base)+7); }while(0)

// ---------------- per-batch-row sequential recurrence (intra-block only) ----
// one block per batch row; 512 threads = 8 waves; thread n owns column n.
// 2 barriers per step. GEMV via v_dot2_f32_f16 with an EXPLICIT double-banked
// register pipeline (two named 8x uint4 banks = 64 VGPRs, 8-16 loads in
// flight, no runtime indexing -> no scratch). r7's full unroll spilled
// (FETCH 5GB); this caps demand at ~110 VGPRs. 1 block/CU -> 128 VGPRs free.
__global__ __launch_bounds__(512, 2) void rnn_layer(
    int layer,
    const float* __restrict__ x,
    float* __restrict__ h_seq,
    const ushort* __restrict__ lnXW,
    ushort* __restrict__ vbuf,
    float* __restrict__ fkbuf,
    float* __restrict__ hvbuf,
    const uint* __restrict__ Upk4,
    const float* __restrict__ ucol,
    const int* __restrict__ mask,
    const float* __restrict__ gam1, const float* __restrict__ bet1,
    const float* __restrict__ bias,
    float* __restrict__ out)
{
  __shared__ __align__(16) ushort tanh16[512];  // f16 tanh (GEMV operand, pair-packed)
  __shared__ __align__(16) float  tanhvf[512];  // f32 tanh (h update / col-512 dot)
  __shared__ float red_a[8], red_q[8], red_p[8];
  __shared__ float sh_v0;
  __shared__ int msk[TT];

  int tid = threadIdx.x;
  int b = blockIdx.x;
  int lane = tid & 63, wid = tid >> 6;
  const bool lastL = (layer == 3);

  float sv = 0.f;                    // own v column
  float v512 = 0.f;                  // uniform on all threads
  float h_lo = 0.f, h_hi = 0.f;
  float fkc = 0.f, hvc = 0.f;        // uniform gate carries
  float g1n = gam1[tid], b1n = bet1[tid];
  float g10 = gam1[0],  b10 = bet1[0];
  float g1e = gam1[512], b1e = bet1[512];
  float bias0 = bias[0];
  float uc = ucol[tid];
  // previous-step gates for the deferred (uniform) col-512 update
  float ho_p = 0.f, xo_p = 0.f, bo_p = 0.f, xu5_p = 0.f;
  int mk_p = 0;

  if (tid < TT) msk[tid] = mask[b * TT + tid];
  if (lane == 0){ red_a[wid] = 0.f; red_q[wid] = 0.f; red_p[wid] = 0.f; }
  if (tid == 0) sh_v0 = 0.f;
  __syncthreads();

  for (int t = 0; t < TT; t++){
    size_t row = (size_t)(t * BB + b);

    // ---- P0: issue this step's loads
    float lw    = bf2f(lnXW[row * NPAD + tid]);
    float lw0   = bf2f(lnXW[row * NPAD]);
    float lw512 = bf2f(lnXW[row * NPAD + 512]);
    float xu    = bf2f(vbuf[row * NPAD + tid]);
    float xu5   = bf2f(vbuf[row * NPAD + 512]);      // broadcast (uniform)
    float xlo, xhi;
    if (layer == 0){ xlo = x[((size_t)(b * TT + t)) * II + tid]; xhi = 0.f; }
    else { xlo = h_seq[row * DD + tid]; xhi = h_seq[row * DD + 512 + tid]; }
    float fkp_tm1 = 0.f, fkp = 0.f, hvp = 1.f;
    if (layer > 0){
      fkp_tm1 = fkbuf[t * BB + b];
      fkp = (t + 1 < TT) ? fkbuf[(t + 1) * BB + b] : 0.f;
      hvp = hvbuf[t * BB + b];
    }
    int mraw  = msk[t];
    int mprev = (t > 0) ? msk[t - 1] : 0;

    // ---- P1: uniform col-512 update (prev step), LN stats, gates (all threads)
    if (t > 0){
      float y512 = red_p[0] + red_p[1] + red_p[2] + red_p[3]
                 + red_p[4] + red_p[5] + red_p[6] + red_p[7];
      float nv5 = ho_p * v512 + xo_p * xu5_p + bo_p * y512;
      if (mk_p) v512 = nv5;
      if (tid == 0 && !lastL) vbuf[(row - BB) * NPAD + 512] = f2bf(v512);
    }
    float S = red_a[0] + red_a[1] + red_a[2] + red_a[3]
            + red_a[4] + red_a[5] + red_a[6] + red_a[7];
    float Q = red_q[0] + red_q[1] + red_q[2] + red_q[3]
            + red_q[4] + red_q[5] + red_q[6] + red_q[7];
    S += v512; Q += v512 * v512;
    float v0 = sh_v0;
    float mean = S * (1.f / 513.f);
    float var  = Q * (1.f / 513.f) - mean * mean;
    float inv  = 1.f / (sqrtf(var + EPSL) + EPSL);

    bool mk  = mraw > 0;
    bool mk2 = (t > 0) && (mprev > 0) && !mk;
    float sum20 = (v0 - mean) * inv * g10 + b10;
    float s0 = lw0 + sum20;
    float fk_both = hsig(s0);
    float fk_t1   = hsig(sum20 + bias0);
    float fk = fkp_tm1 + (1.f - fkp_tm1) * (fkc * fk_both + (1.f - fkc) * fk_t1);
    if (mk2) fk = 0.f;
    float h_only = hvc * fk * (fkp + (1.f - fkp) * (1.f - hvp));
    float x_only = hvp * (1.f - fkp) * (1.f - fk + fk * (1.f - hvc));
    float both   = (1.f - fkp) * fk * hvc * hvp;
    float hv = 1.f - (1.f - h_only) * (1.f - x_only) * (1.f - both);
    fkc = mk ? fk : fkc;
    hvc = mk ? hv : hvc;
    if (mk2) fkc = 0.f;

    // ---- P2: LN apply + tanh; stage f16 (pair-packed via layout) and f32
    {
      float sum2 = (sv - mean) * inv * g1n + b1n;
      float s = lw + sum2;
      float th = ftanh(s);
      if (tid == 0){
        float sum2e = (v512 - mean) * inv * g1e + b1e;
        float the = ftanh(lw512 + sum2e);
        tanh16[511] = __builtin_bit_cast(ushort, (_Float16)the);
        tanhvf[511] = the;
      } else {
        tanh16[tid - 1] = __builtin_bit_cast(ushort, (_Float16)th);
        tanhvf[tid - 1] = th;
      }
    }
    __syncthreads();   // B1: tanh staged

    // ---- P3: GEMV y[n] = sum_k tanh[k] * U_hi[k][n] via fdot2, explicit
    //          double-banked pipeline (banks A/B of 8 uint4; 8-16 in flight)
    float y0 = 0.f, y1 = 0.f, y2 = 0.f, y3 = 0.f;
    {
      const uint4* up = (const uint4*)Upk4 + tid;
      const uint4* tp = (const uint4*)tanh16;
      uint4 a0, a1, a2, a3, a4, a5, a6, a7;
      uint4 n0, n1, n2, n3, n4, n5, n6, n7;
      LD8(a0,a1,a2,a3,a4,a5,a6,a7, 0);           // batch 0 (c 0..7)
#pragma unroll
      for (int k = 0; k < 4; k++){
        const int cb = k * 16;
        LD8(n0,n1,n2,n3,n4,n5,n6,n7, cb + 8);    // prefetch odd batch
        CO8(a0,a1,a2,a3,a4,a5,a6,a7, cb);        // consume even batch
        if (k < 3)
          LD8(a0,a1,a2,a3,a4,a5,a6,a7, cb + 16); // prefetch next even batch
        CO8(n0,n1,n2,n3,n4,n5,n6,n7, cb + 8);    // consume odd batch
      }
    }
    float y = (y0 + y1) + (y2 + y3);
    // col-512 partial: this thread's tanh (core col tid) x U[II+tid][512]
    {
      float p = tanhvf[tid] * uc;
#pragma unroll
      for (int m = 1; m < 64; m <<= 1) p += __shfl_xor(p, m, 64);
      if (lane == 0) red_p[wid] = p;     // read next step (after step-start barrier)
    }

    // ---- P4: state updates, stream writes, next-step LN stats
    float nv = h_only * sv + x_only * xu + both * y;
    if (mk) sv = nv;
    float thh = tanhvf[tid];
    float nh_lo = h_only * h_lo + x_only * xlo;
    float nh_hi = h_only * h_hi + x_only * xhi + both * thh;
    if (mk){ h_lo = nh_lo; h_hi = nh_hi; }
    if (!lastL){
      vbuf[row * NPAD + tid] = f2bf(sv);
      h_seq[row * DD + tid] = h_lo;
      h_seq[row * DD + 512 + tid] = h_hi;
      if (tid == 0){ fkbuf[t * BB + b] = fkc; hvbuf[t * BB + b] = hvc; }
    }
    if (lastL && t == TT - 1) out[b * HH + tid] = h_hi;

    ho_p = h_only; xo_p = x_only; bo_p = both; mk_p = mk ? 1 : 0; xu5_p = xu5;

    {
      float a = sv, q = sv * sv;
#pragma unroll
      for (int m = 1; m < 64; m <<= 1){ a += __shfl_xor(a, m, 64); q += __shfl_xor(q, m, 64); }
      if (lane == 0){ red_a[wid] = a; red_q[wid] = q; }
      if (tid == 0) sh_v0 = sv;
    }
    __syncthreads();   // B2 (= next step's start barrier)
  }

  // epilogue: final col-512 update (t = TT-1)
  if (tid == 0 && !lastL){
    float y512 = red_p[0] + red_p[1] + red_p[2] + red_p[3]
               + red_p[4] + red_p[5] + red_p[6] + red_p[7];
    float nv5 = ho_p * v512 + xo_p * xu5_p + bo_p * y512;
    if (mk_p) v512 = nv5;
    vbuf[(size_t)((TT - 1) * BB + b) * NPAD + 512] = f2bf(v512);
  }
}

extern "C" void kernel_launch(void* const* d_in, const int* in_sizes, int n_in,
                              void* d_out, int out_size, void* d_ws, size_t ws_size,
                              hipStream_t stream)
{
  (void)in_sizes; (void)n_in; (void)out_size; (void)ws_size;
  const float* x      = (const float*)d_in[0];
  const int*   mask   = (const int*)d_in[1];
  const float* W      = (const float*)d_in[2];
  const float* U      = (const float*)d_in[3];
  const float* bias   = (const float*)d_in[4];
  const float* gammas = (const float*)d_in[5];
  const float* betas  = (const float*)d_in[6];
  float* out = (float*)d_out;

  char* ws = (char*)d_ws;
  size_t off = 0;
  auto alloc = [&](size_t bytes) -> void* {
    void* p = ws + off;
    off += (bytes + 255) & ~(size_t)255;
    return p;
  };
  float*  h_seq = (float*) alloc((size_t)TT * BB * DD * 4);
  ushort* lnXW  = (ushort*)alloc((size_t)TT * BB * NPAD * 2);
  ushort* vbuf  = (ushort*)alloc((size_t)TT * BB * NPAD * 2);
  float*  fkbuf = (float*) alloc((size_t)TT * BB * 4);
  float*  hvbuf = (float*) alloc((size_t)TT * BB * 4);
  ushort* Wpk   = (ushort*)alloc((size_t)128 * NT * 16 * 8 * 2);
  ushort* Upk   = (ushort*)alloc((size_t)128 * NT * 16 * 8 * 2);
  uint*   Upk4  = (uint*)  alloc((size_t)64 * 512 * 4 * 4);
  float*  ucol  = (float*) alloc(512 * 4);

  int npk = 128 * NT * 16 * 8;
  prepack_B<<<dim3((npk + 255) / 256), dim3(256), 0, stream>>>(W, Wpk);
  prepack_B<<<dim3((npk + 255) / 256), dim3(256), 0, stream>>>(U, Upk);
  prepack_Uhi_pk<<<dim3((64 * 512 * 4 + 255) / 256), dim3(256), 0, stream>>>(U, Upk4, ucol);

  const float* g0 = gammas,      *g1 = gammas + NC;
  const float* be0 = betas,      *be1 = betas + NC;

  // layer 0: lnXW = LN(x @ W_lo)+b ; vbuf = x @ U_lo (raw)
  gemm_ln<<<dim3(256), dim3(1024), 0, stream>>>(x, 0, 16, Wpk, lnXW, 1, g0, be0, bias);
  gemm_ln<<<dim3(256), dim3(1024), 0, stream>>>(x, 0, 16, Upk, vbuf, 0, g0, be0, bias);
  rnn_layer<<<dim3(BB), dim3(512), 0, stream>>>(0, x, h_seq, lnXW, vbuf, fkbuf, hvbuf,
                                                Upk4, ucol, mask, g1, be1, bias, out);
  for (int d = 1; d < 4; d++){
    gemm_ln<<<dim3(256), dim3(1024), 0, stream>>>(h_seq, 1, 32, Wpk, lnXW, 1, g0, be0, bias);
    rnn_layer<<<dim3(BB), dim3(512), 0, stream>>>(d, x, h_seq, lnXW, vbuf, fkbuf, hvbuf,
                                                  Upk4, ucol, mask, g1, be1, bias, out);
  }
}

// Round 9
// 3054.869 us; speedup vs baseline: 5.4645x; 5.3446x over previous
//
#include <hip/hip_runtime.h>
#include <cstdint>

#define TT 128   // time steps (= bucket_size)
#define BB 128   // batch
#define II 512   // input dim
#define HH 512   // hidden dim
#define DD 1024  // I + H
#define NC 513   // H + 1
#define NPAD 520 // row pitch for lnXW / vbuf (bf16)
#define NT 36    // n-tiles of 16 in big GEMM (576 padded cols)
#define EPSL 1e-5f

typedef short    s8v  __attribute__((ext_vector_type(8)));
typedef float    f4v  __attribute__((ext_vector_type(4)));
typedef _Float16 h2v  __attribute__((ext_vector_type(2)));

__device__ __forceinline__ ushort f2bf(float f){
  uint u = __builtin_bit_cast(uint, f);
  uint r = (u + 0x7fffu + ((u >> 16) & 1u)) >> 16;
  return (ushort)r;
}
__device__ __forceinline__ float bf2f(ushort s){
  uint u = ((uint)s) << 16;
  return __builtin_bit_cast(float, u);
}
__device__ __forceinline__ float hsig(float x){
  return fminf(fmaxf(0.2f * x + 0.5f, 0.f), 1.f);
}
// fast tanh via exp2; |err| ~1e-6
__device__ __forceinline__ float ftanh(float x){
  float ax = fminf(fabsf(x), 15.f);
  float e  = __builtin_amdgcn_exp2f(ax * 2.885390082f);   // 2*log2(e)
  float r  = (e - 1.f) * __builtin_amdgcn_rcpf(e + 1.f);
  return __builtin_copysignf(r, x);
}
// f32 += dot(f16x2, f16x2) — exact products, f32 accumulate
__device__ __forceinline__ float dot2(uint a, uint b, float c){
#if __has_builtin(__builtin_amdgcn_fdot2)
  return __builtin_amdgcn_fdot2(__builtin_bit_cast(h2v, a),
                                __builtin_bit_cast(h2v, b), c, false);
#else
  h2v x = __builtin_bit_cast(h2v, a), y = __builtin_bit_cast(h2v, b);
  return fmaf((float)x[1], (float)y[1], fmaf((float)x[0], (float)y[0], c));
#endif
}

// ---------------- pre-pack W / U into MFMA B-fragment order (bf16, big GEMM) ----
__global__ void prepack_B(const float* __restrict__ src, ushort* __restrict__ dst){
  int idx = blockIdx.x * 256 + threadIdx.x;
  if (idx >= 128 * NT * 16 * 8) return;
  int kl = idx & 7;
  int ni = (idx >> 3) & 15;
  int nt = (idx >> 7) % NT;
  int kc = idx / (NT * 16 * 8);
  int k = kc * 8 + kl;
  int n = nt * 16 + ni;
  float v = (n < NC) ? src[k * NC + n] : 0.f;
  dst[idx] = f2bf(v);
}

// ---------------- pre-pack U_hi (rows II..II+511) as f16 pairs for fdot2 --------
// uint idx = (c*512 + n)*4 + j holds f16 pair (U[II+8c+2j][n], U[II+8c+2j+1][n]).
__global__ void prepack_Uhi_pk(const float* __restrict__ U, uint* __restrict__ dst,
                               float* __restrict__ ucol){
  int idx = blockIdx.x * 256 + threadIdx.x;
  if (idx < 64 * 512 * 4){
    int j = idx & 3;
    int n = (idx >> 2) & 511;
    int c = idx >> 11;
    int k0 = II + 8 * c + 2 * j;
    _Float16 lo = (_Float16)U[(size_t)k0 * NC + n];
    _Float16 hi = (_Float16)U[(size_t)(k0 + 1) * NC + n];
    dst[idx] = (uint)__builtin_bit_cast(ushort, lo)
             | ((uint)__builtin_bit_cast(ushort, hi) << 16);
  }
  if (idx < 512) ucol[idx] = U[(size_t)(II + idx) * NC + 512];
}

// ---------------- fused GEMM (+ optional row-LayerNorm) -------------------
__global__ __launch_bounds__(1024) void gemm_ln(
    const float* __restrict__ A, int amode, int ksteps,
    const ushort* __restrict__ Bpk, ushort* __restrict__ out,
    int do_ln, const float* __restrict__ gam, const float* __restrict__ bet,
    const float* __restrict__ bias)
{
  __shared__ ushort As[64][40];
  __shared__ float red[4][4][16][2];
  int tid = threadIdx.x;
  int lane = tid & 63, wid = tid >> 6;
  int quad = lane >> 4, l16 = lane & 15;
  int wm = wid >> 2, wn = wid & 3;
  int blk = blockIdx.x;

  f4v acc[9];
#pragma unroll
  for (int i = 0; i < 9; i++) acc[i] = (f4v){0.f, 0.f, 0.f, 0.f};

  int arow = tid >> 4;
  int acp  = tid & 15;
  int r = blk * 64 + arow;
  const float* aptr;
  if (amode == 0){ int t = r >> 7, b = r & 127; aptr = A + ((size_t)(b * TT + t)) * II + acp * 2; }
  else           { aptr = A + (size_t)r * DD + acp * 2; }

  for (int ks = 0; ks < ksteps; ks++){
    __syncthreads();
    float2 a2 = *(const float2*)(aptr + ks * 32);
    uint pk = (uint)f2bf(a2.x) | ((uint)f2bf(a2.y) << 16);
    *(uint*)&As[arow][acp * 2] = pk;
    __syncthreads();
    s8v af = *(const s8v*)&As[wm * 16 + l16][quad * 8];
    int kc = ks * 4 + quad;
    const s8v* bp = (const s8v*)Bpk + (size_t)kc * (NT * 16) + l16;
#pragma unroll
    for (int i = 0; i < 9; i++){
      s8v bf = bp[(wn * 9 + i) * 16];
      acc[i] = __builtin_amdgcn_mfma_f32_16x16x32_bf16(af, bf, acc[i], 0, 0, 0);
    }
  }

  int rowbase = blk * 64 + wm * 16 + quad * 4;
  if (do_ln){
    float s1[4], s2[4];
#pragma unroll
    for (int g = 0; g < 4; g++){
      float a = 0.f, q = 0.f;
#pragma unroll
      for (int i = 0; i < 9; i++){ float v = acc[i][g]; a += v; q += v * v; }
#pragma unroll
      for (int m = 1; m < 16; m <<= 1){ a += __shfl_xor(a, m, 64); q += __shfl_xor(q, m, 64); }
      s1[g] = a; s2[g] = q;
    }
    if (l16 == 0){
#pragma unroll
      for (int g = 0; g < 4; g++){
        red[wm][wn][quad * 4 + g][0] = s1[g];
        red[wm][wn][quad * 4 + g][1] = s2[g];
      }
    }
    __syncthreads();
#pragma unroll
    for (int g = 0; g < 4; g++){
      int rr = quad * 4 + g;
      float S1 = red[wm][0][rr][0] + red[wm][1][rr][0] + red[wm][2][rr][0] + red[wm][3][rr][0];
      float S2 = red[wm][0][rr][1] + red[wm][1][rr][1] + red[wm][2][rr][1] + red[wm][3][rr][1];
      float mean = S1 * (1.f / 513.f);
      float var  = S2 * (1.f / 513.f) - mean * mean;
      float inv  = 1.f / (sqrtf(var + EPSL) + EPSL);
      size_t rg = (size_t)(rowbase + g);
#pragma unroll
      for (int i = 0; i < 9; i++){
        int n = wn * 144 + i * 16 + l16;
        if (n < NC){
          float val = gam[n] * ((acc[i][g] - mean) * inv) + bet[n] + bias[n];
          out[rg * NPAD + n] = f2bf(val);
        }
      }
    }
  } else {
#pragma unroll
    for (int g = 0; g < 4; g++){
      size_t rg = (size_t)(rowbase + g);
#pragma unroll
      for (int i = 0; i < 9; i++){
        int n = wn * 144 + i * 16 + l16;
        if (n < NC) out[rg * NPAD + n] = f2bf(acc[i][g]);
      }
    }
  }
}

// ---------------- per-batch-row sequential recurrence (intra-block only) ----
// one block per batch row; 1024 threads = 16 waves. Columns owned by tid<512
// (thread n = column n). GEMV K-SPLIT BY 2: thread n does K in [0,256),
// thread n+512 does K in [256,512); halves combined through LDS ypart.
// Halves the per-thread L2 load chain (32 loads) and doubles waves/SIMD (4)
// for TLP latency hiding — no register pipeline tricks (r7/r8 spilled).
// 3 barriers/step. Numerics identical to the verified r5 kernel.
__global__ __launch_bounds__(1024) void rnn_layer(
    int layer,
    const float* __restrict__ x,
    float* __restrict__ h_seq,
    const ushort* __restrict__ lnXW,
    ushort* __restrict__ vbuf,
    float* __restrict__ fkbuf,
    float* __restrict__ hvbuf,
    const uint* __restrict__ Upk4,
    const float* __restrict__ ucol,
    const int* __restrict__ mask,
    const float* __restrict__ gam1, const float* __restrict__ bet1,
    const float* __restrict__ bias,
    float* __restrict__ out)
{
  __shared__ __align__(16) ushort tanh16[512];  // f16 tanh (GEMV operand, pair-packed)
  __shared__ __align__(16) float  tanhvf[512];  // f32 tanh (h update / col-512 dot)
  __shared__ __align__(16) float  ypart[512];   // upper-half GEMV partials
  __shared__ float red_a[8], red_q[8], red_p[8];
  __shared__ float sh_v0;
  __shared__ int msk[TT];

  int tid = threadIdx.x;             // 0..1023
  const bool lowh = (tid < 512);
  int b = blockIdx.x;
  int lane = tid & 63, wid = tid >> 6;
  const bool lastL = (layer == 3);

  float sv = 0.f;                    // own v column (lower)
  float v512 = 0.f;                  // uniform col-512 state (lower)
  float h_lo = 0.f, h_hi = 0.f;
  float fkc = 0.f, hvc = 0.f;        // uniform gate carries (lower)
  float g1n = lowh ? gam1[tid] : 0.f;
  float b1n = lowh ? bet1[tid] : 0.f;
  float g10 = gam1[0],  b10 = bet1[0];
  float g1e = gam1[512], b1e = bet1[512];
  float bias0 = bias[0];
  float uc = lowh ? ucol[tid] : 0.f;
  // previous-step gates for the deferred (uniform) col-512 update
  float ho_p = 0.f, xo_p = 0.f, bo_p = 0.f, xu5_p = 0.f;
  int mk_p = 0;

  if (tid < TT) msk[tid] = mask[b * TT + tid];
  if (lowh && lane == 0){ red_a[wid] = 0.f; red_q[wid] = 0.f; red_p[wid] = 0.f; }
  if (tid == 0) sh_v0 = 0.f;
  __syncthreads();

  for (int t = 0; t < TT; t++){
    size_t row = (size_t)(t * BB + b);

    // lower-half scalar phases (P0/P1/P2); upper waves pass through to B1
    float h_only = 0.f, x_only = 0.f, both = 0.f;
    float xu = 0.f, xlo = 0.f, xhi = 0.f, xu5 = 0.f;
    bool mk = false;
    if (lowh){
      // ---- P0: issue this step's loads
      float lw    = bf2f(lnXW[row * NPAD + tid]);
      float lw0   = bf2f(lnXW[row * NPAD]);
      float lw512 = bf2f(lnXW[row * NPAD + 512]);
      xu  = bf2f(vbuf[row * NPAD + tid]);
      xu5 = bf2f(vbuf[row * NPAD + 512]);            // broadcast (uniform)
      if (layer == 0){ xlo = x[((size_t)(b * TT + t)) * II + tid]; xhi = 0.f; }
      else { xlo = h_seq[row * DD + tid]; xhi = h_seq[row * DD + 512 + tid]; }
      float fkp_tm1 = 0.f, fkp = 0.f, hvp = 1.f;
      if (layer > 0){
        fkp_tm1 = fkbuf[t * BB + b];
        fkp = (t + 1 < TT) ? fkbuf[(t + 1) * BB + b] : 0.f;
        hvp = hvbuf[t * BB + b];
      }
      int mraw  = msk[t];
      int mprev = (t > 0) ? msk[t - 1] : 0;

      // ---- P1: uniform col-512 update (prev step), LN stats, gates
      if (t > 0){
        float y512 = red_p[0] + red_p[1] + red_p[2] + red_p[3]
                   + red_p[4] + red_p[5] + red_p[6] + red_p[7];
        float nv5 = ho_p * v512 + xo_p * xu5_p + bo_p * y512;
        if (mk_p) v512 = nv5;
        if (tid == 0 && !lastL) vbuf[(row - BB) * NPAD + 512] = f2bf(v512);
      }
      float S = red_a[0] + red_a[1] + red_a[2] + red_a[3]
              + red_a[4] + red_a[5] + red_a[6] + red_a[7];
      float Q = red_q[0] + red_q[1] + red_q[2] + red_q[3]
              + red_q[4] + red_q[5] + red_q[6] + red_q[7];
      S += v512; Q += v512 * v512;
      float v0 = sh_v0;
      float mean = S * (1.f / 513.f);
      float var  = Q * (1.f / 513.f) - mean * mean;
      float inv  = 1.f / (sqrtf(var + EPSL) + EPSL);

      mk = mraw > 0;
      bool mk2 = (t > 0) && (mprev > 0) && !mk;
      float sum20 = (v0 - mean) * inv * g10 + b10;
      float s0 = lw0 + sum20;
      float fk_both = hsig(s0);
      float fk_t1   = hsig(sum20 + bias0);
      float fk = fkp_tm1 + (1.f - fkp_tm1) * (fkc * fk_both + (1.f - fkc) * fk_t1);
      if (mk2) fk = 0.f;
      h_only = hvc * fk * (fkp + (1.f - fkp) * (1.f - hvp));
      x_only = hvp * (1.f - fkp) * (1.f - fk + fk * (1.f - hvc));
      both   = (1.f - fkp) * fk * hvc * hvp;
      float hv = 1.f - (1.f - h_only) * (1.f - x_only) * (1.f - both);
      fkc = mk ? fk : fkc;
      hvc = mk ? hv : hvc;
      if (mk2) fkc = 0.f;

      // ---- P2: LN apply + tanh; stage f16 (pair-packed) and f32
      float sum2 = (sv - mean) * inv * g1n + b1n;
      float s = lw + sum2;
      float th = ftanh(s);
      if (tid == 0){
        float sum2e = (v512 - mean) * inv * g1e + b1e;
        float the = ftanh(lw512 + sum2e);
        tanh16[511] = __builtin_bit_cast(ushort, (_Float16)the);
        tanhvf[511] = the;
      } else {
        tanh16[tid - 1] = __builtin_bit_cast(ushort, (_Float16)th);
        tanhvf[tid - 1] = th;
      }
    }
    __syncthreads();   // B1: tanh staged

    // ---- P3: GEMV, K-split across the two thread halves (32 loads each)
    float yloc;
    {
      int n = tid & 511;
      int cbase = (tid >> 9) * 32;              // 0 for lower, 32 for upper
      const uint4* up = (const uint4*)Upk4 + (size_t)cbase * 512 + n;
      const uint4* tp = (const uint4*)tanh16 + cbase;
      float y0 = 0.f, y1 = 0.f, y2 = 0.f, y3 = 0.f;
#pragma unroll 8
      for (int c = 0; c < 32; c++){
        uint4 uu = up[(size_t)c * 512];         // coalesced 16B/lane (L2)
        uint4 tt = tp[c];                       // LDS broadcast
        y0 = dot2(tt.x, uu.x, y0);
        y1 = dot2(tt.y, uu.y, y1);
        y2 = dot2(tt.z, uu.z, y2);
        y3 = dot2(tt.w, uu.w, y3);
      }
      yloc = (y0 + y1) + (y2 + y3);
      if (!lowh) ypart[n] = yloc;
    }
    // col-512 partial (lower half): tanh[tid] x U[II+tid][512]
    if (lowh){
      float p = tanhvf[tid] * uc;
#pragma unroll
      for (int m = 1; m < 64; m <<= 1) p += __shfl_xor(p, m, 64);
      if (lane == 0) red_p[wid] = p;     // consumed next step after B2
    }
    __syncthreads();   // B1.5: ypart ready

    // ---- P4: state updates, stream writes, next-step LN stats (lower half)
    if (lowh){
      float y = yloc + ypart[tid];
      float nv = h_only * sv + x_only * xu + both * y;
      if (mk) sv = nv;
      float thh = tanhvf[tid];
      float nh_lo = h_only * h_lo + x_only * xlo;
      float nh_hi = h_only * h_hi + x_only * xhi + both * thh;
      if (mk){ h_lo = nh_lo; h_hi = nh_hi; }
      if (!lastL){
        vbuf[row * NPAD + tid] = f2bf(sv);
        h_seq[row * DD + tid] = h_lo;
        h_seq[row * DD + 512 + tid] = h_hi;
        if (tid == 0){ fkbuf[t * BB + b] = fkc; hvbuf[t * BB + b] = hvc; }
      }
      if (lastL && t == TT - 1) out[b * HH + tid] = h_hi;

      ho_p = h_only; xo_p = x_only; bo_p = both; mk_p = mk ? 1 : 0; xu5_p = xu5;

      float a = sv, q = sv * sv;
#pragma unroll
      for (int m = 1; m < 64; m <<= 1){ a += __shfl_xor(a, m, 64); q += __shfl_xor(q, m, 64); }
      if (lane == 0){ red_a[wid] = a; red_q[wid] = q; }
      if (tid == 0) sh_v0 = sv;
    }
    __syncthreads();   // B2 (= next step's start barrier)
  }

  // epilogue: final col-512 update (t = TT-1)
  if (tid == 0 && !lastL){
    float y512 = red_p[0] + red_p[1] + red_p[2] + red_p[3]
               + red_p[4] + red_p[5] + red_p[6] + red_p[7];
    float nv5 = ho_p * v512 + xo_p * xu5_p + bo_p * y512;
    if (mk_p) v512 = nv5;
    vbuf[(size_t)((TT - 1) * BB + b) * NPAD + 512] = f2bf(v512);
  }
}

extern "C" void kernel_launch(void* const* d_in, const int* in_sizes, int n_in,
                              void* d_out, int out_size, void* d_ws, size_t ws_size,
                              hipStream_t stream)
{
  (void)in_sizes; (void)n_in; (void)out_size; (void)ws_size;
  const float* x      = (const float*)d_in[0];
  const int*   mask   = (const int*)d_in[1];
  const float* W      = (const float*)d_in[2];
  const float* U      = (const float*)d_in[3];
  const float* bias   = (const float*)d_in[4];
  const float* gammas = (const float*)d_in[5];
  const float* betas  = (const float*)d_in[6];
  float* out = (float*)d_out;

  char* ws = (char*)d_ws;
  size_t off = 0;
  auto alloc = [&](size_t bytes) -> void* {
    void* p = ws + off;
    off += (bytes + 255) & ~(size_t)255;
    return p;
  };
  float*  h_seq = (float*) alloc((size_t)TT * BB * DD * 4);
  ushort* lnXW  = (ushort*)alloc((size_t)TT * BB * NPAD * 2);
  ushort* vbuf  = (ushort*)alloc((size_t)TT * BB * NPAD * 2);
  float*  fkbuf = (float*) alloc((size_t)TT * BB * 4);
  float*  hvbuf = (float*) alloc((size_t)TT * BB * 4);
  ushort* Wpk   = (ushort*)alloc((size_t)128 * NT * 16 * 8 * 2);
  ushort* Upk   = (ushort*)alloc((size_t)128 * NT * 16 * 8 * 2);
  uint*   Upk4  = (uint*)  alloc((size_t)64 * 512 * 4 * 4);
  float*  ucol  = (float*) alloc(512 * 4);

  int npk = 128 * NT * 16 * 8;
  prepack_B<<<dim3((npk + 255) / 256), dim3(256), 0, stream>>>(W, Wpk);
  prepack_B<<<dim3((npk + 255) / 256), dim3(256), 0, stream>>>(U, Upk);
  prepack_Uhi_pk<<<dim3((64 * 512 * 4 + 255) / 256), dim3(256), 0, stream>>>(U, Upk4, ucol);

  const float* g0 = gammas,      *g1 = gammas + NC;
  const float* be0 = betas,      *be1 = betas + NC;

  // layer 0: lnXW = LN(x @ W_lo)+b ; vbuf = x @ U_lo (raw)
  gemm_ln<<<dim3(256), dim3(1024), 0, stream>>>(x, 0, 16, Wpk, lnXW, 1, g0, be0, bias);
  gemm_ln<<<dim3(256), dim3(1024), 0, stream>>>(x, 0, 16, Upk, vbuf, 0, g0, be0, bias);
  rnn_layer<<<dim3(BB), dim3(1024), 0, stream>>>(0, x, h_seq, lnXW, vbuf, fkbuf, hvbuf,
                                                 Upk4, ucol, mask, g1, be1, bias, out);
  for (int d = 1; d < 4; d++){
    gemm_ln<<<dim3(256), dim3(1024), 0, stream>>>(h_seq, 1, 32, Wpk, lnXW, 1, g0, be0, bias);
    rnn_layer<<<dim3(BB), dim3(1024), 0, stream>>>(d, x, h_seq, lnXW, vbuf, fkbuf, hvbuf,
                                                   Upk4, ucol, mask, g1, be1, bias, out);
  }
}

// Round 11
// 2475.616 us; speedup vs baseline: 6.7431x; 1.2340x over previous
//
#include <hip/hip_runtime.h>
#include <cstdint>

#define TT 128   // time steps (= bucket_size)
#define BB 128   // batch
#define II 512   // input dim
#define HH 512   // hidden dim
#define DD 1024  // I + H
#define NC 513   // H + 1
#define NPAD 520 // row pitch for lnXW / vbuf (bf16)
#define NT 36    // n-tiles of 16 in big GEMM (576 padded cols)
#define EPSL 1e-5f

typedef short    s8v  __attribute__((ext_vector_type(8)));
typedef float    f4v  __attribute__((ext_vector_type(4)));
typedef _Float16 h2v  __attribute__((ext_vector_type(2)));

__device__ __forceinline__ ushort f2bf(float f){
  uint u = __builtin_bit_cast(uint, f);
  uint r = (u + 0x7fffu + ((u >> 16) & 1u)) >> 16;
  return (ushort)r;
}
__device__ __forceinline__ float bf2f(ushort s){
  uint u = ((uint)s) << 16;
  return __builtin_bit_cast(float, u);
}
__device__ __forceinline__ float hsig(float x){
  return fminf(fmaxf(0.2f * x + 0.5f, 0.f), 1.f);
}
// fast tanh via exp2; |err| ~1e-6
__device__ __forceinline__ float ftanh(float x){
  float ax = fminf(fabsf(x), 15.f);
  float e  = __builtin_amdgcn_exp2f(ax * 2.885390082f);   // 2*log2(e)
  float r  = (e - 1.f) * __builtin_amdgcn_rcpf(e + 1.f);
  return __builtin_copysignf(r, x);
}
// f32 += dot(f16x2, f16x2) — exact products, f32 accumulate
__device__ __forceinline__ float dot2(uint a, uint b, float c){
#if __has_builtin(__builtin_amdgcn_fdot2)
  return __builtin_amdgcn_fdot2(__builtin_bit_cast(h2v, a),
                                __builtin_bit_cast(h2v, b), c, false);
#else
  h2v x = __builtin_bit_cast(h2v, a), y = __builtin_bit_cast(h2v, b);
  return fmaf((float)x[1], (float)y[1], fmaf((float)x[0], (float)y[0], c));
#endif
}

// ---------------- pre-pack W / U into MFMA B-fragment order (bf16, big GEMM) ----
__global__ void prepack_B(const float* __restrict__ src, ushort* __restrict__ dst){
  int idx = blockIdx.x * 256 + threadIdx.x;
  if (idx >= 128 * NT * 16 * 8) return;
  int kl = idx & 7;
  int ni = (idx >> 3) & 15;
  int nt = (idx >> 7) % NT;
  int kc = idx / (NT * 16 * 8);
  int k = kc * 8 + kl;
  int n = nt * 16 + ni;
  float v = (n < NC) ? src[k * NC + n] : 0.f;
  dst[idx] = f2bf(v);
}

// ---------------- pre-pack U_hi (rows II..II+511) as f16 pairs for fdot2 --------
// uint idx = (c*512 + n)*4 + j holds f16 pair (U[II+8c+2j][n], U[II+8c+2j+1][n]).
__global__ void prepack_Uhi_pk(const float* __restrict__ U, uint* __restrict__ dst,
                               float* __restrict__ ucol){
  int idx = blockIdx.x * 256 + threadIdx.x;
  if (idx < 64 * 512 * 4){
    int j = idx & 3;
    int n = (idx >> 2) & 511;
    int c = idx >> 11;
    int k0 = II + 8 * c + 2 * j;
    _Float16 lo = (_Float16)U[(size_t)k0 * NC + n];
    _Float16 hi = (_Float16)U[(size_t)(k0 + 1) * NC + n];
    dst[idx] = (uint)__builtin_bit_cast(ushort, lo)
             | ((uint)__builtin_bit_cast(ushort, hi) << 16);
  }
  if (idx < 512) ucol[idx] = U[(size_t)(II + idx) * NC + 512];
}

// ---------------- fused GEMM (+ optional row-LayerNorm) -------------------
__global__ __launch_bounds__(1024) void gemm_ln(
    const float* __restrict__ A, int amode, int ksteps,
    const ushort* __restrict__ Bpk, ushort* __restrict__ out,
    int do_ln, const float* __restrict__ gam, const float* __restrict__ bet,
    const float* __restrict__ bias)
{
  __shared__ ushort As[64][40];
  __shared__ float red[4][4][16][2];
  int tid = threadIdx.x;
  int lane = tid & 63, wid = tid >> 6;
  int quad = lane >> 4, l16 = lane & 15;
  int wm = wid >> 2, wn = wid & 3;
  int blk = blockIdx.x;

  f4v acc[9];
#pragma unroll
  for (int i = 0; i < 9; i++) acc[i] = (f4v){0.f, 0.f, 0.f, 0.f};

  int arow = tid >> 4;
  int acp  = tid & 15;
  int r = blk * 64 + arow;
  const float* aptr;
  if (amode == 0){ int t = r >> 7, b = r & 127; aptr = A + ((size_t)(b * TT + t)) * II + acp * 2; }
  else           { aptr = A + (size_t)r * DD + acp * 2; }

  for (int ks = 0; ks < ksteps; ks++){
    __syncthreads();
    float2 a2 = *(const float2*)(aptr + ks * 32);
    uint pk = (uint)f2bf(a2.x) | ((uint)f2bf(a2.y) << 16);
    *(uint*)&As[arow][acp * 2] = pk;
    __syncthreads();
    s8v af = *(const s8v*)&As[wm * 16 + l16][quad * 8];
    int kc = ks * 4 + quad;
    const s8v* bp = (const s8v*)Bpk + (size_t)kc * (NT * 16) + l16;
#pragma unroll
    for (int i = 0; i < 9; i++){
      s8v bf = bp[(wn * 9 + i) * 16];
      acc[i] = __builtin_amdgcn_mfma_f32_16x16x32_bf16(af, bf, acc[i], 0, 0, 0);
    }
  }

  int rowbase = blk * 64 + wm * 16 + quad * 4;
  if (do_ln){
    float s1[4], s2[4];
#pragma unroll
    for (int g = 0; g < 4; g++){
      float a = 0.f, q = 0.f;
#pragma unroll
      for (int i = 0; i < 9; i++){ float v = acc[i][g]; a += v; q += v * v; }
#pragma unroll
      for (int m = 1; m < 16; m <<= 1){ a += __shfl_xor(a, m, 64); q += __shfl_xor(q, m, 64); }
      s1[g] = a; s2[g] = q;
    }
    if (l16 == 0){
#pragma unroll
      for (int g = 0; g < 4; g++){
        red[wm][wn][quad * 4 + g][0] = s1[g];
        red[wm][wn][quad * 4 + g][1] = s2[g];
      }
    }
    __syncthreads();
#pragma unroll
    for (int g = 0; g < 4; g++){
      int rr = quad * 4 + g;
      float S1 = red[wm][0][rr][0] + red[wm][1][rr][0] + red[wm][2][rr][0] + red[wm][3][rr][0];
      float S2 = red[wm][0][rr][1] + red[wm][1][rr][1] + red[wm][2][rr][1] + red[wm][3][rr][1];
      float mean = S1 * (1.f / 513.f);
      float var  = S2 * (1.f / 513.f) - mean * mean;
      float inv  = 1.f / (sqrtf(var + EPSL) + EPSL);
      size_t rg = (size_t)(rowbase + g);
#pragma unroll
      for (int i = 0; i < 9; i++){
        int n = wn * 144 + i * 16 + l16;
        if (n < NC){
          float val = gam[n] * ((acc[i][g] - mean) * inv) + bet[n] + bias[n];
          out[rg * NPAD + n] = f2bf(val);
        }
      }
    }
  } else {
#pragma unroll
    for (int g = 0; g < 4; g++){
      size_t rg = (size_t)(rowbase + g);
#pragma unroll
      for (int i = 0; i < 9; i++){
        int n = wn * 144 + i * 16 + l16;
        if (n < NC) out[rg * NPAD + n] = f2bf(acc[i][g]);
      }
    }
  }
}

// consume one register-resident U chunk
#define COREG(r, c) do{ uint4 tt = tp[(c)];                        \
  y0 = dot2(tt.x, r.x, y0); y1 = dot2(tt.y, r.y, y1);              \
  y2 = dot2(tt.z, r.z, y2); y3 = dot2(tt.w, r.w, y3); }while(0)

// pin a uint4's components in VGPRs (32-bit tied constraints are supported;
// 128-bit tuples are not — r10 compile failure)
#define PIN4(r) asm volatile("" : "+v"(r.x), "+v"(r.y), "+v"(r.z), "+v"(r.w))

// ---------------- per-batch-row sequential recurrence (intra-block only) ----
// one block per batch row; 1024 threads = 16 waves; K-split by 2 (r9).
// U is 3-TIERED per half (32 chunks of 8 KB): 9 chunks LDS-resident (staged
// once; 147 KB static LDS, separate pipe from L1), 8 chunks register-resident
// (32 VGPRs, pinned per-component with loop-carried "+v" asm so they CANNOT
// be re-loaded), 15 chunks streamed from L2. Bytes through L1/step: 512->240 KB.
// r9 showed the binding constraint is per-CU L1 fill bandwidth; this is the
// byte-reduction lever. Numerics identical (same f16 values, new sum order).
__global__ __launch_bounds__(1024) void rnn_layer(
    int layer,
    const float* __restrict__ x,
    float* __restrict__ h_seq,
    const ushort* __restrict__ lnXW,
    ushort* __restrict__ vbuf,
    float* __restrict__ fkbuf,
    float* __restrict__ hvbuf,
    const uint* __restrict__ Upk4,
    const float* __restrict__ ucol,
    const int* __restrict__ mask,
    const float* __restrict__ gam1, const float* __restrict__ bet1,
    const float* __restrict__ bias,
    float* __restrict__ out)
{
  __shared__ __align__(16) uint4  u_lds[18 * 512];  // 147456 B: 9 chunks/half
  __shared__ __align__(16) ushort tanh16[512];  // f16 tanh (GEMV operand)
  __shared__ __align__(16) float  tanhvf[512];  // f32 tanh (h update / col-512 dot)
  __shared__ __align__(16) float  ypart[512];   // upper-half GEMV partials
  __shared__ float red_a[8], red_q[8], red_p[8];
  __shared__ float sh_v0;
  __shared__ int msk[TT];

  int tid = threadIdx.x;             // 0..1023
  const bool lowh = (tid < 512);
  int b = blockIdx.x;
  int lane = tid & 63, wid = tid >> 6;
  const bool lastL = (layer == 3);

  float sv = 0.f;                    // own v column (lower)
  float v512 = 0.f;                  // uniform col-512 state (lower)
  float h_lo = 0.f, h_hi = 0.f;
  float fkc = 0.f, hvc = 0.f;        // uniform gate carries (lower)
  float g1n = lowh ? gam1[tid] : 0.f;
  float b1n = lowh ? bet1[tid] : 0.f;
  float g10 = gam1[0],  b10 = bet1[0];
  float g1e = gam1[512], b1e = bet1[512];
  float bias0 = bias[0];
  float uc = lowh ? ucol[tid] : 0.f;
  // previous-step gates for the deferred (uniform) col-512 update
  float ho_p = 0.f, xo_p = 0.f, bo_p = 0.f, xu5_p = 0.f;
  int mk_p = 0;

  // ---- stage LDS-resident U chunks (lower: c 0..8 -> slot 0..8;
  //      upper: c 32..40 -> slot 9..17); one-time
  {
    const uint4* U4 = (const uint4*)Upk4;
    for (int i = tid; i < 18 * 512; i += 1024){
      int slot = i >> 9, n2 = i & 511;
      int c = (slot < 9) ? slot : 32 + (slot - 9);
      u_lds[i] = U4[(size_t)c * 512 + n2];
    }
  }

  // ---- register-resident U chunks: per half c = cbase+9 .. cbase+16
  int n_ = tid & 511;
  int cbase_ = (tid >> 9) * 32;
  uint4 ur0, ur1, ur2, ur3, ur4, ur5, ur6, ur7;
  {
    const uint4* upr = (const uint4*)Upk4 + (size_t)(cbase_ + 9) * 512 + n_;
    ur0 = upr[0 * 512]; ur1 = upr[1 * 512]; ur2 = upr[2 * 512]; ur3 = upr[3 * 512];
    ur4 = upr[4 * 512]; ur5 = upr[5 * 512]; ur6 = upr[6 * 512]; ur7 = upr[7 * 512];
  }

  if (tid < TT) msk[tid] = mask[b * TT + tid];
  if (lowh && lane == 0){ red_a[wid] = 0.f; red_q[wid] = 0.f; red_p[wid] = 0.f; }
  if (tid == 0) sh_v0 = 0.f;
  __syncthreads();

  for (int t = 0; t < TT; t++){
    // pin register-resident chunks: loop-carried "+v" makes reload impossible
    PIN4(ur0); PIN4(ur1); PIN4(ur2); PIN4(ur3);
    PIN4(ur4); PIN4(ur5); PIN4(ur6); PIN4(ur7);

    size_t row = (size_t)(t * BB + b);

    // lower-half scalar phases (P0/P1/P2); upper waves pass through to B1
    float h_only = 0.f, x_only = 0.f, both = 0.f;
    float xu = 0.f, xlo = 0.f, xhi = 0.f, xu5 = 0.f;
    bool mk = false;
    if (lowh){
      // ---- P0: issue this step's loads
      float lw    = bf2f(lnXW[row * NPAD + tid]);
      float lw0   = bf2f(lnXW[row * NPAD]);
      float lw512 = bf2f(lnXW[row * NPAD + 512]);
      xu  = bf2f(vbuf[row * NPAD + tid]);
      xu5 = bf2f(vbuf[row * NPAD + 512]);            // broadcast (uniform)
      if (layer == 0){ xlo = x[((size_t)(b * TT + t)) * II + tid]; xhi = 0.f; }
      else { xlo = h_seq[row * DD + tid]; xhi = h_seq[row * DD + 512 + tid]; }
      float fkp_tm1 = 0.f, fkp = 0.f, hvp = 1.f;
      if (layer > 0){
        fkp_tm1 = fkbuf[t * BB + b];
        fkp = (t + 1 < TT) ? fkbuf[(t + 1) * BB + b] : 0.f;
        hvp = hvbuf[t * BB + b];
      }
      int mraw  = msk[t];
      int mprev = (t > 0) ? msk[t - 1] : 0;

      // ---- P1: uniform col-512 update (prev step), LN stats, gates
      if (t > 0){
        float y512 = red_p[0] + red_p[1] + red_p[2] + red_p[3]
                   + red_p[4] + red_p[5] + red_p[6] + red_p[7];
        float nv5 = ho_p * v512 + xo_p * xu5_p + bo_p * y512;
        if (mk_p) v512 = nv5;
        if (tid == 0 && !lastL) vbuf[(row - BB) * NPAD + 512] = f2bf(v512);
      }
      float S = red_a[0] + red_a[1] + red_a[2] + red_a[3]
              + red_a[4] + red_a[5] + red_a[6] + red_a[7];
      float Q = red_q[0] + red_q[1] + red_q[2] + red_q[3]
              + red_q[4] + red_q[5] + red_q[6] + red_q[7];
      S += v512; Q += v512 * v512;
      float v0 = sh_v0;
      float mean = S * (1.f / 513.f);
      float var  = Q * (1.f / 513.f) - mean * mean;
      float inv  = 1.f / (sqrtf(var + EPSL) + EPSL);

      mk = mraw > 0;
      bool mk2 = (t > 0) && (mprev > 0) && !mk;
      float sum20 = (v0 - mean) * inv * g10 + b10;
      float s0 = lw0 + sum20;
      float fk_both = hsig(s0);
      float fk_t1   = hsig(sum20 + bias0);
      float fk = fkp_tm1 + (1.f - fkp_tm1) * (fkc * fk_both + (1.f - fkc) * fk_t1);
      if (mk2) fk = 0.f;
      h_only = hvc * fk * (fkp + (1.f - fkp) * (1.f - hvp));
      x_only = hvp * (1.f - fkp) * (1.f - fk + fk * (1.f - hvc));
      both   = (1.f - fkp) * fk * hvc * hvp;
      float hv = 1.f - (1.f - h_only) * (1.f - x_only) * (1.f - both);
      fkc = mk ? fk : fkc;
      hvc = mk ? hv : hvc;
      if (mk2) fkc = 0.f;

      // ---- P2: LN apply + tanh; stage f16 (pair-packed) and f32
      float sum2 = (sv - mean) * inv * g1n + b1n;
      float s = lw + sum2;
      float th = ftanh(s);
      if (tid == 0){
        float sum2e = (v512 - mean) * inv * g1e + b1e;
        float the = ftanh(lw512 + sum2e);
        tanh16[511] = __builtin_bit_cast(ushort, (_Float16)the);
        tanhvf[511] = the;
      } else {
        tanh16[tid - 1] = __builtin_bit_cast(ushort, (_Float16)th);
        tanhvf[tid - 1] = th;
      }
    }
    __syncthreads();   // B1: tanh staged

    // ---- P3: GEMV, K-split; U from 3 tiers: stream(15) + regs(8) + LDS(9)
    float yloc;
    {
      const uint4* tp = (const uint4*)tanh16;
      const uint4* ups = (const uint4*)Upk4 + (size_t)(cbase_ + 17) * 512 + n_;
      float y0 = 0.f, y1 = 0.f, y2 = 0.f, y3 = 0.f;
      // tier 1: L2 stream (issue early; bounded unroll -> no spill)
#pragma unroll 6
      for (int c = 0; c < 15; c++){
        uint4 uu = ups[(size_t)c * 512];        // coalesced 16B/lane (L2)
        uint4 tt = tp[cbase_ + 17 + c];         // LDS broadcast
        y0 = dot2(tt.x, uu.x, y0);
        y1 = dot2(tt.y, uu.y, y1);
        y2 = dot2(tt.z, uu.z, y2);
        y3 = dot2(tt.w, uu.w, y3);
      }
      // tier 2: register-resident chunks (zero memory traffic)
      COREG(ur0, cbase_ + 9);  COREG(ur1, cbase_ + 10);
      COREG(ur2, cbase_ + 11); COREG(ur3, cbase_ + 12);
      COREG(ur4, cbase_ + 13); COREG(ur5, cbase_ + 14);
      COREG(ur6, cbase_ + 15); COREG(ur7, cbase_ + 16);
      // tier 3: LDS-resident chunks (separate pipe, overlaps the L2 stream)
      const uint4* ul = u_lds + (size_t)(tid >> 9) * (9 * 512) + n_;
#pragma unroll
      for (int j = 0; j < 9; j++){
        uint4 uu = ul[j * 512];
        uint4 tt = tp[cbase_ + j];
        y0 = dot2(tt.x, uu.x, y0);
        y1 = dot2(tt.y, uu.y, y1);
        y2 = dot2(tt.z, uu.z, y2);
        y3 = dot2(tt.w, uu.w, y3);
      }
      yloc = (y0 + y1) + (y2 + y3);
      if (!lowh) ypart[n_] = yloc;
    }
    // col-512 partial (lower half): tanh[tid] x U[II+tid][512]
    if (lowh){
      float p = tanhvf[tid] * uc;
#pragma unroll
      for (int m = 1; m < 64; m <<= 1) p += __shfl_xor(p, m, 64);
      if (lane == 0) red_p[wid] = p;     // consumed next step after B2
    }
    __syncthreads();   // B1.5: ypart ready

    // ---- P4: state updates, stream writes, next-step LN stats (lower half)
    if (lowh){
      float y = yloc + ypart[tid];
      float nv = h_only * sv + x_only * xu + both * y;
      if (mk) sv = nv;
      float thh = tanhvf[tid];
      float nh_lo = h_only * h_lo + x_only * xlo;
      float nh_hi = h_only * h_hi + x_only * xhi + both * thh;
      if (mk){ h_lo = nh_lo; h_hi = nh_hi; }
      if (!lastL){
        vbuf[row * NPAD + tid] = f2bf(sv);
        h_seq[row * DD + tid] = h_lo;
        h_seq[row * DD + 512 + tid] = h_hi;
        if (tid == 0){ fkbuf[t * BB + b] = fkc; hvbuf[t * BB + b] = hvc; }
      }
      if (lastL && t == TT - 1) out[b * HH + tid] = h_hi;

      ho_p = h_only; xo_p = x_only; bo_p = both; mk_p = mk ? 1 : 0; xu5_p = xu5;

      float a = sv, q = sv * sv;
#pragma unroll
      for (int m = 1; m < 64; m <<= 1){ a += __shfl_xor(a, m, 64); q += __shfl_xor(q, m, 64); }
      if (lane == 0){ red_a[wid] = a; red_q[wid] = q; }
      if (tid == 0) sh_v0 = sv;
    }
    __syncthreads();   // B2 (= next step's start barrier)
  }

  // epilogue: final col-512 update (t = TT-1)
  if (tid == 0 && !lastL){
    float y512 = red_p[0] + red_p[1] + red_p[2] + red_p[3]
               + red_p[4] + red_p[5] + red_p[6] + red_p[7];
    float nv5 = ho_p * v512 + xo_p * xu5_p + bo_p * y512;
    if (mk_p) v512 = nv5;
    vbuf[(size_t)((TT - 1) * BB + b) * NPAD + 512] = f2bf(v512);
  }
}

extern "C" void kernel_launch(void* const* d_in, const int* in_sizes, int n_in,
                              void* d_out, int out_size, void* d_ws, size_t ws_size,
                              hipStream_t stream)
{
  (void)in_sizes; (void)n_in; (void)out_size; (void)ws_size;
  const float* x      = (const float*)d_in[0];
  const int*   mask   = (const int*)d_in[1];
  const float* W      = (const float*)d_in[2];
  const float* U      = (const float*)d_in[3];
  const float* bias   = (const float*)d_in[4];
  const float* gammas = (const float*)d_in[5];
  const float* betas  = (const float*)d_in[6];
  float* out = (float*)d_out;

  char* ws = (char*)d_ws;
  size_t off = 0;
  auto alloc = [&](size_t bytes) -> void* {
    void* p = ws + off;
    off += (bytes + 255) & ~(size_t)255;
    return p;
  };
  float*  h_seq = (float*) alloc((size_t)TT * BB * DD * 4);
  ushort* lnXW  = (ushort*)alloc((size_t)TT * BB * NPAD * 2);
  ushort* vbuf  = (ushort*)alloc((size_t)TT * BB * NPAD * 2);
  float*  fkbuf = (float*) alloc((size_t)TT * BB * 4);
  float*  hvbuf = (float*) alloc((size_t)TT * BB * 4);
  ushort* Wpk   = (ushort*)alloc((size_t)128 * NT * 16 * 8 * 2);
  ushort* Upk   = (ushort*)alloc((size_t)128 * NT * 16 * 8 * 2);
  uint*   Upk4  = (uint*)  alloc((size_t)64 * 512 * 4 * 4);
  float*  ucol  = (float*) alloc(512 * 4);

  int npk = 128 * NT * 16 * 8;
  prepack_B<<<dim3((npk + 255) / 256), dim3(256), 0, stream>>>(W, Wpk);
  prepack_B<<<dim3((npk + 255) / 256), dim3(256), 0, stream>>>(U, Upk);
  prepack_Uhi_pk<<<dim3((64 * 512 * 4 + 255) / 256), dim3(256), 0, stream>>>(U, Upk4, ucol);

  const float* g0 = gammas,      *g1 = gammas + NC;
  const float* be0 = betas,      *be1 = betas + NC;

  // layer 0: lnXW = LN(x @ W_lo)+b ; vbuf = x @ U_lo (raw)
  gemm_ln<<<dim3(256), dim3(1024), 0, stream>>>(x, 0, 16, Wpk, lnXW, 1, g0, be0, bias);
  gemm_ln<<<dim3(256), dim3(1024), 0, stream>>>(x, 0, 16, Upk, vbuf, 0, g0, be0, bias);
  rnn_layer<<<dim3(BB), dim3(1024), 0, stream>>>(0, x, h_seq, lnXW, vbuf, fkbuf, hvbuf,
                                                 Upk4, ucol, mask, g1, be1, bias, out);
  for (int d = 1; d < 4; d++){
    gemm_ln<<<dim3(256), dim3(1024), 0, stream>>>(h_seq, 1, 32, Wpk, lnXW, 1, g0, be0, bias);
    rnn_layer<<<dim3(BB), dim3(1024), 0, stream>>>(d, x, h_seq, lnXW, vbuf, fkbuf, hvbuf,
                                                   Upk4, ucol, mask, g1, be1, bias, out);
  }
}

// Round 12
// 2475.129 us; speedup vs baseline: 6.7445x; 1.0002x over previous
//
#include <hip/hip_runtime.h>
#include <cstdint>

#define TT 128   // time steps (= bucket_size)
#define BB 128   // batch
#define II 512   // input dim
#define HH 512   // hidden dim
#define DD 1024  // I + H
#define NC 513   // H + 1
#define NPAD 520 // row pitch for lnXW / vbuf (bf16)
#define NT 36    // n-tiles of 16 in big GEMM (576 padded cols)
#define EPSL 1e-5f

typedef short    s8v  __attribute__((ext_vector_type(8)));
typedef float    f4v  __attribute__((ext_vector_type(4)));
typedef _Float16 h2v  __attribute__((ext_vector_type(2)));

__device__ __forceinline__ ushort f2bf(float f){
  uint u = __builtin_bit_cast(uint, f);
  uint r = (u + 0x7fffu + ((u >> 16) & 1u)) >> 16;
  return (ushort)r;
}
__device__ __forceinline__ float bf2f(ushort s){
  uint u = ((uint)s) << 16;
  return __builtin_bit_cast(float, u);
}
__device__ __forceinline__ float hsig(float x){
  return fminf(fmaxf(0.2f * x + 0.5f, 0.f), 1.f);
}
// fast tanh via exp2; |err| ~1e-6
__device__ __forceinline__ float ftanh(float x){
  float ax = fminf(fabsf(x), 15.f);
  float e  = __builtin_amdgcn_exp2f(ax * 2.885390082f);   // 2*log2(e)
  float r  = (e - 1.f) * __builtin_amdgcn_rcpf(e + 1.f);
  return __builtin_copysignf(r, x);
}
// f32 += dot(f16x2, f16x2) — exact products, f32 accumulate
__device__ __forceinline__ float dot2(uint a, uint b, float c){
#if __has_builtin(__builtin_amdgcn_fdot2)
  return __builtin_amdgcn_fdot2(__builtin_bit_cast(h2v, a),
                                __builtin_bit_cast(h2v, b), c, false);
#else
  h2v x = __builtin_bit_cast(h2v, a), y = __builtin_bit_cast(h2v, b);
  return fmaf((float)x[1], (float)y[1], fmaf((float)x[0], (float)y[0], c));
#endif
}

// ---------------- pre-pack W / U into MFMA B-fragment order (bf16, big GEMM) ----
__global__ void prepack_B(const float* __restrict__ src, ushort* __restrict__ dst){
  int idx = blockIdx.x * 256 + threadIdx.x;
  if (idx >= 128 * NT * 16 * 8) return;
  int kl = idx & 7;
  int ni = (idx >> 3) & 15;
  int nt = (idx >> 7) % NT;
  int kc = idx / (NT * 16 * 8);
  int k = kc * 8 + kl;
  int n = nt * 16 + ni;
  float v = (n < NC) ? src[k * NC + n] : 0.f;
  dst[idx] = f2bf(v);
}

// ---------------- pre-pack U_hi (rows II..II+511) as f16 pairs for fdot2 --------
// uint idx = (c*512 + n)*4 + j holds f16 pair (U[II+8c+2j][n], U[II+8c+2j+1][n]).
__global__ void prepack_Uhi_pk(const float* __restrict__ U, uint* __restrict__ dst,
                               float* __restrict__ ucol){
  int idx = blockIdx.x * 256 + threadIdx.x;
  if (idx < 64 * 512 * 4){
    int j = idx & 3;
    int n = (idx >> 2) & 511;
    int c = idx >> 11;
    int k0 = II + 8 * c + 2 * j;
    _Float16 lo = (_Float16)U[(size_t)k0 * NC + n];
    _Float16 hi = (_Float16)U[(size_t)(k0 + 1) * NC + n];
    dst[idx] = (uint)__builtin_bit_cast(ushort, lo)
             | ((uint)__builtin_bit_cast(ushort, hi) << 16);
  }
  if (idx < 512) ucol[idx] = U[(size_t)(II + idx) * NC + 512];
}

// ---------------- fused GEMM (+ optional row-LayerNorm) -------------------
__global__ __launch_bounds__(1024) void gemm_ln(
    const float* __restrict__ A, int amode, int ksteps,
    const ushort* __restrict__ Bpk, ushort* __restrict__ out,
    int do_ln, const float* __restrict__ gam, const float* __restrict__ bet,
    const float* __restrict__ bias)
{
  __shared__ ushort As[64][40];
  __shared__ float red[4][4][16][2];
  int tid = threadIdx.x;
  int lane = tid & 63, wid = tid >> 6;
  int quad = lane >> 4, l16 = lane & 15;
  int wm = wid >> 2, wn = wid & 3;
  int blk = blockIdx.x;

  f4v acc[9];
#pragma unroll
  for (int i = 0; i < 9; i++) acc[i] = (f4v){0.f, 0.f, 0.f, 0.f};

  int arow = tid >> 4;
  int acp  = tid & 15;
  int r = blk * 64 + arow;
  const float* aptr;
  if (amode == 0){ int t = r >> 7, b = r & 127; aptr = A + ((size_t)(b * TT + t)) * II + acp * 2; }
  else           { aptr = A + (size_t)r * DD + acp * 2; }

  for (int ks = 0; ks < ksteps; ks++){
    __syncthreads();
    float2 a2 = *(const float2*)(aptr + ks * 32);
    uint pk = (uint)f2bf(a2.x) | ((uint)f2bf(a2.y) << 16);
    *(uint*)&As[arow][acp * 2] = pk;
    __syncthreads();
    s8v af = *(const s8v*)&As[wm * 16 + l16][quad * 8];
    int kc = ks * 4 + quad;
    const s8v* bp = (const s8v*)Bpk + (size_t)kc * (NT * 16) + l16;
#pragma unroll
    for (int i = 0; i < 9; i++){
      s8v bf = bp[(wn * 9 + i) * 16];
      acc[i] = __builtin_amdgcn_mfma_f32_16x16x32_bf16(af, bf, acc[i], 0, 0, 0);
    }
  }

  int rowbase = blk * 64 + wm * 16 + quad * 4;
  if (do_ln){
    float s1[4], s2[4];
#pragma unroll
    for (int g = 0; g < 4; g++){
      float a = 0.f, q = 0.f;
#pragma unroll
      for (int i = 0; i < 9; i++){ float v = acc[i][g]; a += v; q += v * v; }
#pragma unroll
      for (int m = 1; m < 16; m <<= 1){ a += __shfl_xor(a, m, 64); q += __shfl_xor(q, m, 64); }
      s1[g] = a; s2[g] = q;
    }
    if (l16 == 0){
#pragma unroll
      for (int g = 0; g < 4; g++){
        red[wm][wn][quad * 4 + g][0] = s1[g];
        red[wm][wn][quad * 4 + g][1] = s2[g];
      }
    }
    __syncthreads();
#pragma unroll
    for (int g = 0; g < 4; g++){
      int rr = quad * 4 + g;
      float S1 = red[wm][0][rr][0] + red[wm][1][rr][0] + red[wm][2][rr][0] + red[wm][3][rr][0];
      float S2 = red[wm][0][rr][1] + red[wm][1][rr][1] + red[wm][2][rr][1] + red[wm][3][rr][1];
      float mean = S1 * (1.f / 513.f);
      float var  = S2 * (1.f / 513.f) - mean * mean;
      float inv  = 1.f / (sqrtf(var + EPSL) + EPSL);
      size_t rg = (size_t)(rowbase + g);
#pragma unroll
      for (int i = 0; i < 9; i++){
        int n = wn * 144 + i * 16 + l16;
        if (n < NC){
          float val = gam[n] * ((acc[i][g] - mean) * inv) + bet[n] + bias[n];
          out[rg * NPAD + n] = f2bf(val);
        }
      }
    }
  } else {
#pragma unroll
    for (int g = 0; g < 4; g++){
      size_t rg = (size_t)(rowbase + g);
#pragma unroll
      for (int i = 0; i < 9; i++){
        int n = wn * 144 + i * 16 + l16;
        if (n < NC) out[rg * NPAD + n] = f2bf(acc[i][g]);
      }
    }
  }
}

// consume one register-resident U chunk
#define COREG(r, c) do{ uint4 tt = tp[(c)];                        \
  y0 = dot2(tt.x, r.x, y0); y1 = dot2(tt.y, r.y, y1);              \
  y2 = dot2(tt.z, r.z, y2); y3 = dot2(tt.w, r.w, y3); }while(0)

// pin a uint4's components in VGPRs (32-bit tied constraints are supported;
// 128-bit tuples are not — r10 compile failure)
#define PIN4(r) asm volatile("" : "+v"(r.x), "+v"(r.y), "+v"(r.z), "+v"(r.w))

// ---------------- per-batch-row sequential recurrence (intra-block only) ----
// one block per batch row; 1024 threads = 16 waves; K-split by 2 (r9).
// U is 3-TIERED per half (32 chunks of 8 KB): 9 chunks LDS-resident (staged
// once; 147 KB static LDS), 16 chunks REGISTER-resident (64 VGPRs, pinned
// per-component so they cannot be re-loaded), 7 chunks streamed from L2.
// Bytes through L1 per step: 512 KB (r9) -> 240 KB (r11) -> 112 KB (this).
// r11 confirmed L1 fill bandwidth is the binding constraint (-21% from the
// first notch); this is the second notch on the same lever. VGPR budget:
// 64 pinned + ~30 stream in-flight + ~20 misc ~= 115 < 128 cap (4 w/SIMD).
__global__ __launch_bounds__(1024) void rnn_layer(
    int layer,
    const float* __restrict__ x,
    float* __restrict__ h_seq,
    const ushort* __restrict__ lnXW,
    ushort* __restrict__ vbuf,
    float* __restrict__ fkbuf,
    float* __restrict__ hvbuf,
    const uint* __restrict__ Upk4,
    const float* __restrict__ ucol,
    const int* __restrict__ mask,
    const float* __restrict__ gam1, const float* __restrict__ bet1,
    const float* __restrict__ bias,
    float* __restrict__ out)
{
  __shared__ __align__(16) uint4  u_lds[18 * 512];  // 147456 B: 9 chunks/half
  __shared__ __align__(16) ushort tanh16[512];  // f16 tanh (GEMV operand)
  __shared__ __align__(16) float  tanhvf[512];  // f32 tanh (h update / col-512 dot)
  __shared__ __align__(16) float  ypart[512];   // upper-half GEMV partials
  __shared__ float red_a[8], red_q[8], red_p[8];
  __shared__ float sh_v0;
  __shared__ int msk[TT];

  int tid = threadIdx.x;             // 0..1023
  const bool lowh = (tid < 512);
  int b = blockIdx.x;
  int lane = tid & 63, wid = tid >> 6;
  const bool lastL = (layer == 3);

  float sv = 0.f;                    // own v column (lower)
  float v512 = 0.f;                  // uniform col-512 state (lower)
  float h_lo = 0.f, h_hi = 0.f;
  float fkc = 0.f, hvc = 0.f;        // uniform gate carries (lower)
  float g1n = lowh ? gam1[tid] : 0.f;
  float b1n = lowh ? bet1[tid] : 0.f;
  float g10 = gam1[0],  b10 = bet1[0];
  float g1e = gam1[512], b1e = bet1[512];
  float bias0 = bias[0];
  float uc = lowh ? ucol[tid] : 0.f;
  // previous-step gates for the deferred (uniform) col-512 update
  float ho_p = 0.f, xo_p = 0.f, bo_p = 0.f, xu5_p = 0.f;
  int mk_p = 0;

  // ---- stage LDS-resident U chunks (lower: c 0..8 -> slot 0..8;
  //      upper: c 32..40 -> slot 9..17); one-time
  {
    const uint4* U4 = (const uint4*)Upk4;
    for (int i = tid; i < 18 * 512; i += 1024){
      int slot = i >> 9, n2 = i & 511;
      int c = (slot < 9) ? slot : 32 + (slot - 9);
      u_lds[i] = U4[(size_t)c * 512 + n2];
    }
  }

  // ---- register-resident U chunks: per half c = cbase+9 .. cbase+24
  int n_ = tid & 511;
  int cbase_ = (tid >> 9) * 32;
  uint4 ur0, ur1, ur2, ur3, ur4, ur5, ur6, ur7;
  uint4 ur8, ur9, urA, urB, urC, urD, urE, urF;
  {
    const uint4* upr = (const uint4*)Upk4 + (size_t)(cbase_ + 9) * 512 + n_;
    ur0 = upr[ 0 * 512]; ur1 = upr[ 1 * 512]; ur2 = upr[ 2 * 512]; ur3 = upr[ 3 * 512];
    ur4 = upr[ 4 * 512]; ur5 = upr[ 5 * 512]; ur6 = upr[ 6 * 512]; ur7 = upr[ 7 * 512];
    ur8 = upr[ 8 * 512]; ur9 = upr[ 9 * 512]; urA = upr[10 * 512]; urB = upr[11 * 512];
    urC = upr[12 * 512]; urD = upr[13 * 512]; urE = upr[14 * 512]; urF = upr[15 * 512];
  }

  if (tid < TT) msk[tid] = mask[b * TT + tid];
  if (lowh && lane == 0){ red_a[wid] = 0.f; red_q[wid] = 0.f; red_p[wid] = 0.f; }
  if (tid == 0) sh_v0 = 0.f;
  __syncthreads();

  for (int t = 0; t < TT; t++){
    // pin register-resident chunks: loop-carried "+v" makes reload impossible
    PIN4(ur0); PIN4(ur1); PIN4(ur2); PIN4(ur3);
    PIN4(ur4); PIN4(ur5); PIN4(ur6); PIN4(ur7);
    PIN4(ur8); PIN4(ur9); PIN4(urA); PIN4(urB);
    PIN4(urC); PIN4(urD); PIN4(urE); PIN4(urF);

    size_t row = (size_t)(t * BB + b);

    // lower-half scalar phases (P0/P1/P2); upper waves pass through to B1
    float h_only = 0.f, x_only = 0.f, both = 0.f;
    float xu = 0.f, xlo = 0.f, xhi = 0.f, xu5 = 0.f;
    bool mk = false;
    if (lowh){
      // ---- P0: issue this step's loads
      float lw    = bf2f(lnXW[row * NPAD + tid]);
      float lw0   = bf2f(lnXW[row * NPAD]);
      float lw512 = bf2f(lnXW[row * NPAD + 512]);
      xu  = bf2f(vbuf[row * NPAD + tid]);
      xu5 = bf2f(vbuf[row * NPAD + 512]);            // broadcast (uniform)
      if (layer == 0){ xlo = x[((size_t)(b * TT + t)) * II + tid]; xhi = 0.f; }
      else { xlo = h_seq[row * DD + tid]; xhi = h_seq[row * DD + 512 + tid]; }
      float fkp_tm1 = 0.f, fkp = 0.f, hvp = 1.f;
      if (layer > 0){
        fkp_tm1 = fkbuf[t * BB + b];
        fkp = (t + 1 < TT) ? fkbuf[(t + 1) * BB + b] : 0.f;
        hvp = hvbuf[t * BB + b];
      }
      int mraw  = msk[t];
      int mprev = (t > 0) ? msk[t - 1] : 0;

      // ---- P1: uniform col-512 update (prev step), LN stats, gates
      if (t > 0){
        float y512 = red_p[0] + red_p[1] + red_p[2] + red_p[3]
                   + red_p[4] + red_p[5] + red_p[6] + red_p[7];
        float nv5 = ho_p * v512 + xo_p * xu5_p + bo_p * y512;
        if (mk_p) v512 = nv5;
        if (tid == 0 && !lastL) vbuf[(row - BB) * NPAD + 512] = f2bf(v512);
      }
      float S = red_a[0] + red_a[1] + red_a[2] + red_a[3]
              + red_a[4] + red_a[5] + red_a[6] + red_a[7];
      float Q = red_q[0] + red_q[1] + red_q[2] + red_q[3]
              + red_q[4] + red_q[5] + red_q[6] + red_q[7];
      S += v512; Q += v512 * v512;
      float v0 = sh_v0;
      float mean = S * (1.f / 513.f);
      float var  = Q * (1.f / 513.f) - mean * mean;
      float inv  = 1.f / (sqrtf(var + EPSL) + EPSL);

      mk = mraw > 0;
      bool mk2 = (t > 0) && (mprev > 0) && !mk;
      float sum20 = (v0 - mean) * inv * g10 + b10;
      float s0 = lw0 + sum20;
      float fk_both = hsig(s0);
      float fk_t1   = hsig(sum20 + bias0);
      float fk = fkp_tm1 + (1.f - fkp_tm1) * (fkc * fk_both + (1.f - fkc) * fk_t1);
      if (mk2) fk = 0.f;
      h_only = hvc * fk * (fkp + (1.f - fkp) * (1.f - hvp));
      x_only = hvp * (1.f - fkp) * (1.f - fk + fk * (1.f - hvc));
      both   = (1.f - fkp) * fk * hvc * hvp;
      float hv = 1.f - (1.f - h_only) * (1.f - x_only) * (1.f - both);
      fkc = mk ? fk : fkc;
      hvc = mk ? hv : hvc;
      if (mk2) fkc = 0.f;

      // ---- P2: LN apply + tanh; stage f16 (pair-packed) and f32
      float sum2 = (sv - mean) * inv * g1n + b1n;
      float s = lw + sum2;
      float th = ftanh(s);
      if (tid == 0){
        float sum2e = (v512 - mean) * inv * g1e + b1e;
        float the = ftanh(lw512 + sum2e);
        tanh16[511] = __builtin_bit_cast(ushort, (_Float16)the);
        tanhvf[511] = the;
      } else {
        tanh16[tid - 1] = __builtin_bit_cast(ushort, (_Float16)th);
        tanhvf[tid - 1] = th;
      }
    }
    __syncthreads();   // B1: tanh staged

    // ---- P3: GEMV, K-split; U tiers: stream(7) + regs(16) + LDS(9)
    float yloc;
    {
      const uint4* tp = (const uint4*)tanh16;
      const uint4* ups = (const uint4*)Upk4 + (size_t)(cbase_ + 25) * 512 + n_;
      float y0 = 0.f, y1 = 0.f, y2 = 0.f, y3 = 0.f;
      // tier 1: L2 stream (issue early; bounded unroll -> no spill)
#pragma unroll 4
      for (int c = 0; c < 7; c++){
        uint4 uu = ups[(size_t)c * 512];        // coalesced 16B/lane (L2)
        uint4 tt = tp[cbase_ + 25 + c];         // LDS broadcast
        y0 = dot2(tt.x, uu.x, y0);
        y1 = dot2(tt.y, uu.y, y1);
        y2 = dot2(tt.z, uu.z, y2);
        y3 = dot2(tt.w, uu.w, y3);
      }
      // tier 2: register-resident chunks (zero memory traffic)
      COREG(ur0, cbase_ +  9); COREG(ur1, cbase_ + 10);
      COREG(ur2, cbase_ + 11); COREG(ur3, cbase_ + 12);
      COREG(ur4, cbase_ + 13); COREG(ur5, cbase_ + 14);
      COREG(ur6, cbase_ + 15); COREG(ur7, cbase_ + 16);
      COREG(ur8, cbase_ + 17); COREG(ur9, cbase_ + 18);
      COREG(urA, cbase_ + 19); COREG(urB, cbase_ + 20);
      COREG(urC, cbase_ + 21); COREG(urD, cbase_ + 22);
      COREG(urE, cbase_ + 23); COREG(urF, cbase_ + 24);
      // tier 3: LDS-resident chunks (separate pipe, overlaps the L2 stream)
      const uint4* ul = u_lds + (size_t)(tid >> 9) * (9 * 512) + n_;
#pragma unroll
      for (int j = 0; j < 9; j++){
        uint4 uu = ul[j * 512];
        uint4 tt = tp[cbase_ + j];
        y0 = dot2(tt.x, uu.x, y0);
        y1 = dot2(tt.y, uu.y, y1);
        y2 = dot2(tt.z, uu.z, y2);
        y3 = dot2(tt.w, uu.w, y3);
      }
      yloc = (y0 + y1) + (y2 + y3);
      if (!lowh) ypart[n_] = yloc;
    }
    // col-512 partial (lower half): tanh[tid] x U[II+tid][512]
    if (lowh){
      float p = tanhvf[tid] * uc;
#pragma unroll
      for (int m = 1; m < 64; m <<= 1) p += __shfl_xor(p, m, 64);
      if (lane == 0) red_p[wid] = p;     // consumed next step after B2
    }
    __syncthreads();   // B1.5: ypart ready

    // ---- P4: state updates, stream writes, next-step LN stats (lower half)
    if (lowh){
      float y = yloc + ypart[tid];
      float nv = h_only * sv + x_only * xu + both * y;
      if (mk) sv = nv;
      float thh = tanhvf[tid];
      float nh_lo = h_only * h_lo + x_only * xlo;
      float nh_hi = h_only * h_hi + x_only * xhi + both * thh;
      if (mk){ h_lo = nh_lo; h_hi = nh_hi; }
      if (!lastL){
        vbuf[row * NPAD + tid] = f2bf(sv);
        h_seq[row * DD + tid] = h_lo;
        h_seq[row * DD + 512 + tid] = h_hi;
        if (tid == 0){ fkbuf[t * BB + b] = fkc; hvbuf[t * BB + b] = hvc; }
      }
      if (lastL && t == TT - 1) out[b * HH + tid] = h_hi;

      ho_p = h_only; xo_p = x_only; bo_p = both; mk_p = mk ? 1 : 0; xu5_p = xu5;

      float a = sv, q = sv * sv;
#pragma unroll
      for (int m = 1; m < 64; m <<= 1){ a += __shfl_xor(a, m, 64); q += __shfl_xor(q, m, 64); }
      if (lane == 0){ red_a[wid] = a; red_q[wid] = q; }
      if (tid == 0) sh_v0 = sv;
    }
    __syncthreads();   // B2 (= next step's start barrier)
  }

  // epilogue: final col-512 update (t = TT-1)
  if (tid == 0 && !lastL){
    float y512 = red_p[0] + red_p[1] + red_p[2] + red_p[3]
               + red_p[4] + red_p[5] + red_p[6] + red_p[7];
    float nv5 = ho_p * v512 + xo_p * xu5_p + bo_p * y512;
    if (mk_p) v512 = nv5;
    vbuf[(size_t)((TT - 1) * BB + b) * NPAD + 512] = f2bf(v512);
  }
}

extern "C" void kernel_launch(void* const* d_in, const int* in_sizes, int n_in,
                              void* d_out, int out_size, void* d_ws, size_t ws_size,
                              hipStream_t stream)
{
  (void)in_sizes; (void)n_in; (void)out_size; (void)ws_size;
  const float* x      = (const float*)d_in[0];
  const int*   mask   = (const int*)d_in[1];
  const float* W      = (const float*)d_in[2];
  const float* U      = (const float*)d_in[3];
  const float* bias   = (const float*)d_in[4];
  const float* gammas = (const float*)d_in[5];
  const float* betas  = (const float*)d_in[6];
  float* out = (float*)d_out;

  char* ws = (char*)d_ws;
  size_t off = 0;
  auto alloc = [&](size_t bytes) -> void* {
    void* p = ws + off;
    off += (bytes + 255) & ~(size_t)255;
    return p;
  };
  float*  h_seq = (float*) alloc((size_t)TT * BB * DD * 4);
  ushort* lnXW  = (ushort*)alloc((size_t)TT * BB * NPAD * 2);
  ushort* vbuf  = (ushort*)alloc((size_t)TT * BB * NPAD * 2);
  float*  fkbuf = (float*) alloc((size_t)TT * BB * 4);
  float*  hvbuf = (float*) alloc((size_t)TT * BB * 4);
  ushort* Wpk   = (ushort*)alloc((size_t)128 * NT * 16 * 8 * 2);
  ushort* Upk   = (ushort*)alloc((size_t)128 * NT * 16 * 8 * 2);
  uint*   Upk4  = (uint*)  alloc((size_t)64 * 512 * 4 * 4);
  float*  ucol  = (float*) alloc(512 * 4);

  int npk = 128 * NT * 16 * 8;
  prepack_B<<<dim3((npk + 255) / 256), dim3(256), 0, stream>>>(W, Wpk);
  prepack_B<<<dim3((npk + 255) / 256), dim3(256), 0, stream>>>(U, Upk);
  prepack_Uhi_pk<<<dim3((64 * 512 * 4 + 255) / 256), dim3(256), 0, stream>>>(U, Upk4, ucol);

  const float* g0 = gammas,      *g1 = gammas + NC;
  const float* be0 = betas,      *be1 = betas + NC;

  // layer 0: lnXW = LN(x @ W_lo)+b ; vbuf = x @ U_lo (raw)
  gemm_ln<<<dim3(256), dim3(1024), 0, stream>>>(x, 0, 16, Wpk, lnXW, 1, g0, be0, bias);
  gemm_ln<<<dim3(256), dim3(1024), 0, stream>>>(x, 0, 16, Upk, vbuf, 0, g0, be0, bias);
  rnn_layer<<<dim3(BB), dim3(1024), 0, stream>>>(0, x, h_seq, lnXW, vbuf, fkbuf, hvbuf,
                                                 Upk4, ucol, mask, g1, be1, bias, out);
  for (int d = 1; d < 4; d++){
    gemm_ln<<<dim3(256), dim3(1024), 0, stream>>>(h_seq, 1, 32, Wpk, lnXW, 1, g0, be0, bias);
    rnn_layer<<<dim3(BB), dim3(1024), 0, stream>>>(d, x, h_seq, lnXW, vbuf, fkbuf, hvbuf,
                                                   Upk4, ucol, mask, g1, be1, bias, out);
  }
}

// Round 13
// 2471.530 us; speedup vs baseline: 6.7543x; 1.0015x over previous
//
#include <hip/hip_runtime.h>
#include <cstdint>

#define TT 128   // time steps (= bucket_size)
#define BB 128   // batch
#define II 512   // input dim
#define HH 512   // hidden dim
#define DD 1024  // I + H
#define NC 513   // H + 1
#define NPAD 520 // row pitch for lnXW / vbuf (bf16)
#define NT 36    // n-tiles of 16 in big GEMM (576 padded cols)
#define EPSL 1e-5f

typedef short    s8v  __attribute__((ext_vector_type(8)));
typedef float    f4v  __attribute__((ext_vector_type(4)));
typedef _Float16 h2v  __attribute__((ext_vector_type(2)));

__device__ __forceinline__ ushort f2bf(float f){
  uint u = __builtin_bit_cast(uint, f);
  uint r = (u + 0x7fffu + ((u >> 16) & 1u)) >> 16;
  return (ushort)r;
}
__device__ __forceinline__ float bf2f(ushort s){
  uint u = ((uint)s) << 16;
  return __builtin_bit_cast(float, u);
}
__device__ __forceinline__ float hsig(float x){
  return fminf(fmaxf(0.2f * x + 0.5f, 0.f), 1.f);
}
// fast tanh via exp2; |err| ~1e-6
__device__ __forceinline__ float ftanh(float x){
  float ax = fminf(fabsf(x), 15.f);
  float e  = __builtin_amdgcn_exp2f(ax * 2.885390082f);   // 2*log2(e)
  float r  = (e - 1.f) * __builtin_amdgcn_rcpf(e + 1.f);
  return __builtin_copysignf(r, x);
}
// f32 += dot(f16x2, f16x2) — exact products, f32 accumulate
__device__ __forceinline__ float dot2(uint a, uint b, float c){
#if __has_builtin(__builtin_amdgcn_fdot2)
  return __builtin_amdgcn_fdot2(__builtin_bit_cast(h2v, a),
                                __builtin_bit_cast(h2v, b), c, false);
#else
  h2v x = __builtin_bit_cast(h2v, a), y = __builtin_bit_cast(h2v, b);
  return fmaf((float)x[1], (float)y[1], fmaf((float)x[0], (float)y[0], c));
#endif
}

// ---------------- pre-pack W / U into MFMA B-fragment order (bf16, big GEMM) ----
__global__ void prepack_B(const float* __restrict__ src, ushort* __restrict__ dst){
  int idx = blockIdx.x * 256 + threadIdx.x;
  if (idx >= 128 * NT * 16 * 8) return;
  int kl = idx & 7;
  int ni = (idx >> 3) & 15;
  int nt = (idx >> 7) % NT;
  int kc = idx / (NT * 16 * 8);
  int k = kc * 8 + kl;
  int n = nt * 16 + ni;
  float v = (n < NC) ? src[k * NC + n] : 0.f;
  dst[idx] = f2bf(v);
}

// ---------------- pre-pack U_hi (rows II..II+511) as f16 pairs for fdot2 --------
// uint idx = (c*512 + n)*4 + j holds f16 pair (U[II+8c+2j][n], U[II+8c+2j+1][n]).
__global__ void prepack_Uhi_pk(const float* __restrict__ U, uint* __restrict__ dst,
                               float* __restrict__ ucol){
  int idx = blockIdx.x * 256 + threadIdx.x;
  if (idx < 64 * 512 * 4){
    int j = idx & 3;
    int n = (idx >> 2) & 511;
    int c = idx >> 11;
    int k0 = II + 8 * c + 2 * j;
    _Float16 lo = (_Float16)U[(size_t)k0 * NC + n];
    _Float16 hi = (_Float16)U[(size_t)(k0 + 1) * NC + n];
    dst[idx] = (uint)__builtin_bit_cast(ushort, lo)
             | ((uint)__builtin_bit_cast(ushort, hi) << 16);
  }
  if (idx < 512) ucol[idx] = U[(size_t)(II + idx) * NC + 512];
}

// ---------------- fused GEMM (+ optional row-LayerNorm) -------------------
__global__ __launch_bounds__(1024) void gemm_ln(
    const float* __restrict__ A, int amode, int ksteps,
    const ushort* __restrict__ Bpk, ushort* __restrict__ out,
    int do_ln, const float* __restrict__ gam, const float* __restrict__ bet,
    const float* __restrict__ bias)
{
  __shared__ ushort As[64][40];
  __shared__ float red[4][4][16][2];
  int tid = threadIdx.x;
  int lane = tid & 63, wid = tid >> 6;
  int quad = lane >> 4, l16 = lane & 15;
  int wm = wid >> 2, wn = wid & 3;
  int blk = blockIdx.x;

  f4v acc[9];
#pragma unroll
  for (int i = 0; i < 9; i++) acc[i] = (f4v){0.f, 0.f, 0.f, 0.f};

  int arow = tid >> 4;
  int acp  = tid & 15;
  int r = blk * 64 + arow;
  const float* aptr;
  if (amode == 0){ int t = r >> 7, b = r & 127; aptr = A + ((size_t)(b * TT + t)) * II + acp * 2; }
  else           { aptr = A + (size_t)r * DD + acp * 2; }

  for (int ks = 0; ks < ksteps; ks++){
    __syncthreads();
    float2 a2 = *(const float2*)(aptr + ks * 32);
    uint pk = (uint)f2bf(a2.x) | ((uint)f2bf(a2.y) << 16);
    *(uint*)&As[arow][acp * 2] = pk;
    __syncthreads();
    s8v af = *(const s8v*)&As[wm * 16 + l16][quad * 8];
    int kc = ks * 4 + quad;
    const s8v* bp = (const s8v*)Bpk + (size_t)kc * (NT * 16) + l16;
#pragma unroll
    for (int i = 0; i < 9; i++){
      s8v bf = bp[(wn * 9 + i) * 16];
      acc[i] = __builtin_amdgcn_mfma_f32_16x16x32_bf16(af, bf, acc[i], 0, 0, 0);
    }
  }

  int rowbase = blk * 64 + wm * 16 + quad * 4;
  if (do_ln){
    float s1[4], s2[4];
#pragma unroll
    for (int g = 0; g < 4; g++){
      float a = 0.f, q = 0.f;
#pragma unroll
      for (int i = 0; i < 9; i++){ float v = acc[i][g]; a += v; q += v * v; }
#pragma unroll
      for (int m = 1; m < 16; m <<= 1){ a += __shfl_xor(a, m, 64); q += __shfl_xor(q, m, 64); }
      s1[g] = a; s2[g] = q;
    }
    if (l16 == 0){
#pragma unroll
      for (int g = 0; g < 4; g++){
        red[wm][wn][quad * 4 + g][0] = s1[g];
        red[wm][wn][quad * 4 + g][1] = s2[g];
      }
    }
    __syncthreads();
#pragma unroll
    for (int g = 0; g < 4; g++){
      int rr = quad * 4 + g;
      float S1 = red[wm][0][rr][0] + red[wm][1][rr][0] + red[wm][2][rr][0] + red[wm][3][rr][0];
      float S2 = red[wm][0][rr][1] + red[wm][1][rr][1] + red[wm][2][rr][1] + red[wm][3][rr][1];
      float mean = S1 * (1.f / 513.f);
      float var  = S2 * (1.f / 513.f) - mean * mean;
      float inv  = 1.f / (sqrtf(var + EPSL) + EPSL);
      size_t rg = (size_t)(rowbase + g);
#pragma unroll
      for (int i = 0; i < 9; i++){
        int n = wn * 144 + i * 16 + l16;
        if (n < NC){
          float val = gam[n] * ((acc[i][g] - mean) * inv) + bet[n] + bias[n];
          out[rg * NPAD + n] = f2bf(val);
        }
      }
    }
  } else {
#pragma unroll
    for (int g = 0; g < 4; g++){
      size_t rg = (size_t)(rowbase + g);
#pragma unroll
      for (int i = 0; i < 9; i++){
        int n = wn * 144 + i * 16 + l16;
        if (n < NC) out[rg * NPAD + n] = f2bf(acc[i][g]);
      }
    }
  }
}

// consume one register-resident U chunk
#define COREG(r, c) do{ uint4 tt = tp[(c)];                        \
  y0 = dot2(tt.x, r.x, y0); y1 = dot2(tt.y, r.y, y1);              \
  y2 = dot2(tt.z, r.z, y2); y3 = dot2(tt.w, r.w, y3); }while(0)

// pin a uint4's components in VGPRs (32-bit tied constraints are supported;
// 128-bit tuples are not — r10 compile failure)
#define PIN4(r) asm volatile("" : "+v"(r.x), "+v"(r.y), "+v"(r.z), "+v"(r.w))

// ---------------- per-batch-row sequential recurrence (intra-block only) ----
// one block per batch row; 1024 threads = 16 waves; K-split by 2 (r9).
// U is 3-TIERED per half (32 chunks of 8 KB): 9 chunks LDS-resident (147 KB),
// 16 chunks REGISTER-resident (64 VGPRs, pinned per-component), 7 chunks
// streamed from L2. Bytes through L1/step: 512 -> 112 KB.
// KEY FIX vs r12: __launch_bounds__(1024, 4). r12's default bounds let the
// heuristic cap VGPR at 64 (targeting 2 blocks/CU) — but occupancy is
// LDS-BOUND at 1 block/CU (153.6/160 KB), so the 64-cap bought nothing and
// forced the compiler to rematerialize the "pinned" chunks from L2 every
// step (r12 == r11 in time, VGPR stuck at 64). min-4-waves/SIMD raises the
// cap to 128: 64 pinned + ~16 stream-in-flight + ~25 misc ~= 105 fits.
__global__ __launch_bounds__(1024, 4) void rnn_layer(
    int layer,
    const float* __restrict__ x,
    float* __restrict__ h_seq,
    const ushort* __restrict__ lnXW,
    ushort* __restrict__ vbuf,
    float* __restrict__ fkbuf,
    float* __restrict__ hvbuf,
    const uint* __restrict__ Upk4,
    const float* __restrict__ ucol,
    const int* __restrict__ mask,
    const float* __restrict__ gam1, const float* __restrict__ bet1,
    const float* __restrict__ bias,
    float* __restrict__ out)
{
  __shared__ __align__(16) uint4  u_lds[18 * 512];  // 147456 B: 9 chunks/half
  __shared__ __align__(16) ushort tanh16[512];  // f16 tanh (GEMV operand)
  __shared__ __align__(16) float  tanhvf[512];  // f32 tanh (h update / col-512 dot)
  __shared__ __align__(16) float  ypart[512];   // upper-half GEMV partials
  __shared__ float red_a[8], red_q[8], red_p[8];
  __shared__ float sh_v0;
  __shared__ int msk[TT];

  int tid = threadIdx.x;             // 0..1023
  const bool lowh = (tid < 512);
  int b = blockIdx.x;
  int lane = tid & 63, wid = tid >> 6;
  const bool lastL = (layer == 3);

  float sv = 0.f;                    // own v column (lower)
  float v512 = 0.f;                  // uniform col-512 state (lower)
  float h_lo = 0.f, h_hi = 0.f;
  float fkc = 0.f, hvc = 0.f;        // uniform gate carries (lower)
  float g1n = lowh ? gam1[tid] : 0.f;
  float b1n = lowh ? bet1[tid] : 0.f;
  float g10 = gam1[0],  b10 = bet1[0];
  float g1e = gam1[512], b1e = bet1[512];
  float bias0 = bias[0];
  float uc = lowh ? ucol[tid] : 0.f;
  // previous-step gates for the deferred (uniform) col-512 update
  float ho_p = 0.f, xo_p = 0.f, bo_p = 0.f, xu5_p = 0.f;
  int mk_p = 0;

  // ---- stage LDS-resident U chunks (lower: c 0..8 -> slot 0..8;
  //      upper: c 32..40 -> slot 9..17); one-time
  {
    const uint4* U4 = (const uint4*)Upk4;
    for (int i = tid; i < 18 * 512; i += 1024){
      int slot = i >> 9, n2 = i & 511;
      int c = (slot < 9) ? slot : 32 + (slot - 9);
      u_lds[i] = U4[(size_t)c * 512 + n2];
    }
  }

  // ---- register-resident U chunks: per half c = cbase+9 .. cbase+24
  int n_ = tid & 511;
  int cbase_ = (tid >> 9) * 32;
  uint4 ur0, ur1, ur2, ur3, ur4, ur5, ur6, ur7;
  uint4 ur8, ur9, urA, urB, urC, urD, urE, urF;
  {
    const uint4* upr = (const uint4*)Upk4 + (size_t)(cbase_ + 9) * 512 + n_;
    ur0 = upr[ 0 * 512]; ur1 = upr[ 1 * 512]; ur2 = upr[ 2 * 512]; ur3 = upr[ 3 * 512];
    ur4 = upr[ 4 * 512]; ur5 = upr[ 5 * 512]; ur6 = upr[ 6 * 512]; ur7 = upr[ 7 * 512];
    ur8 = upr[ 8 * 512]; ur9 = upr[ 9 * 512]; urA = upr[10 * 512]; urB = upr[11 * 512];
    urC = upr[12 * 512]; urD = upr[13 * 512]; urE = upr[14 * 512]; urF = upr[15 * 512];
  }

  if (tid < TT) msk[tid] = mask[b * TT + tid];
  if (lowh && lane == 0){ red_a[wid] = 0.f; red_q[wid] = 0.f; red_p[wid] = 0.f; }
  if (tid == 0) sh_v0 = 0.f;
  __syncthreads();

  for (int t = 0; t < TT; t++){
    // pin register-resident chunks: loop-carried "+v" makes reload impossible
    PIN4(ur0); PIN4(ur1); PIN4(ur2); PIN4(ur3);
    PIN4(ur4); PIN4(ur5); PIN4(ur6); PIN4(ur7);
    PIN4(ur8); PIN4(ur9); PIN4(urA); PIN4(urB);
    PIN4(urC); PIN4(urD); PIN4(urE); PIN4(urF);

    size_t row = (size_t)(t * BB + b);

    // lower-half scalar phases (P0/P1/P2); upper waves pass through to B1
    float h_only = 0.f, x_only = 0.f, both = 0.f;
    float xu = 0.f, xlo = 0.f, xhi = 0.f, xu5 = 0.f;
    bool mk = false;
    if (lowh){
      // ---- P0: issue this step's loads
      float lw    = bf2f(lnXW[row * NPAD + tid]);
      float lw0   = bf2f(lnXW[row * NPAD]);
      float lw512 = bf2f(lnXW[row * NPAD + 512]);
      xu  = bf2f(vbuf[row * NPAD + tid]);
      xu5 = bf2f(vbuf[row * NPAD + 512]);            // broadcast (uniform)
      if (layer == 0){ xlo = x[((size_t)(b * TT + t)) * II + tid]; xhi = 0.f; }
      else { xlo = h_seq[row * DD + tid]; xhi = h_seq[row * DD + 512 + tid]; }
      float fkp_tm1 = 0.f, fkp = 0.f, hvp = 1.f;
      if (layer > 0){
        fkp_tm1 = fkbuf[t * BB + b];
        fkp = (t + 1 < TT) ? fkbuf[(t + 1) * BB + b] : 0.f;
        hvp = hvbuf[t * BB + b];
      }
      int mraw  = msk[t];
      int mprev = (t > 0) ? msk[t - 1] : 0;

      // ---- P1: uniform col-512 update (prev step), LN stats, gates
      if (t > 0){
        float y512 = red_p[0] + red_p[1] + red_p[2] + red_p[3]
                   + red_p[4] + red_p[5] + red_p[6] + red_p[7];
        float nv5 = ho_p * v512 + xo_p * xu5_p + bo_p * y512;
        if (mk_p) v512 = nv5;
        if (tid == 0 && !lastL) vbuf[(row - BB) * NPAD + 512] = f2bf(v512);
      }
      float S = red_a[0] + red_a[1] + red_a[2] + red_a[3]
              + red_a[4] + red_a[5] + red_a[6] + red_a[7];
      float Q = red_q[0] + red_q[1] + red_q[2] + red_q[3]
              + red_q[4] + red_q[5] + red_q[6] + red_q[7];
      S += v512; Q += v512 * v512;
      float v0 = sh_v0;
      float mean = S * (1.f / 513.f);
      float var  = Q * (1.f / 513.f) - mean * mean;
      float inv  = 1.f / (sqrtf(var + EPSL) + EPSL);

      mk = mraw > 0;
      bool mk2 = (t > 0) && (mprev > 0) && !mk;
      float sum20 = (v0 - mean) * inv * g10 + b10;
      float s0 = lw0 + sum20;
      float fk_both = hsig(s0);
      float fk_t1   = hsig(sum20 + bias0);
      float fk = fkp_tm1 + (1.f - fkp_tm1) * (fkc * fk_both + (1.f - fkc) * fk_t1);
      if (mk2) fk = 0.f;
      h_only = hvc * fk * (fkp + (1.f - fkp) * (1.f - hvp));
      x_only = hvp * (1.f - fkp) * (1.f - fk + fk * (1.f - hvc));
      both   = (1.f - fkp) * fk * hvc * hvp;
      float hv = 1.f - (1.f - h_only) * (1.f - x_only) * (1.f - both);
      fkc = mk ? fk : fkc;
      hvc = mk ? hv : hvc;
      if (mk2) fkc = 0.f;

      // ---- P2: LN apply + tanh; stage f16 (pair-packed) and f32
      float sum2 = (sv - mean) * inv * g1n + b1n;
      float s = lw + sum2;
      float th = ftanh(s);
      if (tid == 0){
        float sum2e = (v512 - mean) * inv * g1e + b1e;
        float the = ftanh(lw512 + sum2e);
        tanh16[511] = __builtin_bit_cast(ushort, (_Float16)the);
        tanhvf[511] = the;
      } else {
        tanh16[tid - 1] = __builtin_bit_cast(ushort, (_Float16)th);
        tanhvf[tid - 1] = th;
      }
    }
    __syncthreads();   // B1: tanh staged

    // ---- P3: GEMV, K-split; U tiers: stream(7) + regs(16) + LDS(9)
    float yloc;
    {
      const uint4* tp = (const uint4*)tanh16;
      const uint4* ups = (const uint4*)Upk4 + (size_t)(cbase_ + 25) * 512 + n_;
      float y0 = 0.f, y1 = 0.f, y2 = 0.f, y3 = 0.f;
      // tier 1: L2 stream (issue early; bounded unroll -> no spill)
#pragma unroll 4
      for (int c = 0; c < 7; c++){
        uint4 uu = ups[(size_t)c * 512];        // coalesced 16B/lane (L2)
        uint4 tt = tp[cbase_ + 25 + c];         // LDS broadcast
        y0 = dot2(tt.x, uu.x, y0);
        y1 = dot2(tt.y, uu.y, y1);
        y2 = dot2(tt.z, uu.z, y2);
        y3 = dot2(tt.w, uu.w, y3);
      }
      // tier 2: register-resident chunks (zero memory traffic)
      COREG(ur0, cbase_ +  9); COREG(ur1, cbase_ + 10);
      COREG(ur2, cbase_ + 11); COREG(ur3, cbase_ + 12);
      COREG(ur4, cbase_ + 13); COREG(ur5, cbase_ + 14);
      COREG(ur6, cbase_ + 15); COREG(ur7, cbase_ + 16);
      COREG(ur8, cbase_ + 17); COREG(ur9, cbase_ + 18);
      COREG(urA, cbase_ + 19); COREG(urB, cbase_ + 20);
      COREG(urC, cbase_ + 21); COREG(urD, cbase_ + 22);
      COREG(urE, cbase_ + 23); COREG(urF, cbase_ + 24);
      // tier 3: LDS-resident chunks (separate pipe, overlaps the L2 stream)
      const uint4* ul = u_lds + (size_t)(tid >> 9) * (9 * 512) + n_;
#pragma unroll
      for (int j = 0; j < 9; j++){
        uint4 uu = ul[j * 512];
        uint4 tt = tp[cbase_ + j];
        y0 = dot2(tt.x, uu.x, y0);
        y1 = dot2(tt.y, uu.y, y1);
        y2 = dot2(tt.z, uu.z, y2);
        y3 = dot2(tt.w, uu.w, y3);
      }
      yloc = (y0 + y1) + (y2 + y3);
      if (!lowh) ypart[n_] = yloc;
    }
    // col-512 partial (lower half): tanh[tid] x U[II+tid][512]
    if (lowh){
      float p = tanhvf[tid] * uc;
#pragma unroll
      for (int m = 1; m < 64; m <<= 1) p += __shfl_xor(p, m, 64);
      if (lane == 0) red_p[wid] = p;     // consumed next step after B2
    }
    __syncthreads();   // B1.5: ypart ready

    // ---- P4: state updates, stream writes, next-step LN stats (lower half)
    if (lowh){
      float y = yloc + ypart[tid];
      float nv = h_only * sv + x_only * xu + both * y;
      if (mk) sv = nv;
      float thh = tanhvf[tid];
      float nh_lo = h_only * h_lo + x_only * xlo;
      float nh_hi = h_only * h_hi + x_only * xhi + both * thh;
      if (mk){ h_lo = nh_lo; h_hi = nh_hi; }
      if (!lastL){
        vbuf[row * NPAD + tid] = f2bf(sv);
        h_seq[row * DD + tid] = h_lo;
        h_seq[row * DD + 512 + tid] = h_hi;
        if (tid == 0){ fkbuf[t * BB + b] = fkc; hvbuf[t * BB + b] = hvc; }
      }
      if (lastL && t == TT - 1) out[b * HH + tid] = h_hi;

      ho_p = h_only; xo_p = x_only; bo_p = both; mk_p = mk ? 1 : 0; xu5_p = xu5;

      float a = sv, q = sv * sv;
#pragma unroll
      for (int m = 1; m < 64; m <<= 1){ a += __shfl_xor(a, m, 64); q += __shfl_xor(q, m, 64); }
      if (lane == 0){ red_a[wid] = a; red_q[wid] = q; }
      if (tid == 0) sh_v0 = sv;
    }
    __syncthreads();   // B2 (= next step's start barrier)
  }

  // epilogue: final col-512 update (t = TT-1)
  if (tid == 0 && !lastL){
    float y512 = red_p[0] + red_p[1] + red_p[2] + red_p[3]
               + red_p[4] + red_p[5] + red_p[6] + red_p[7];
    float nv5 = ho_p * v512 + xo_p * xu5_p + bo_p * y512;
    if (mk_p) v512 = nv5;
    vbuf[(size_t)((TT - 1) * BB + b) * NPAD + 512] = f2bf(v512);
  }
}

extern "C" void kernel_launch(void* const* d_in, const int* in_sizes, int n_in,
                              void* d_out, int out_size, void* d_ws, size_t ws_size,
                              hipStream_t stream)
{
  (void)in_sizes; (void)n_in; (void)out_size; (void)ws_size;
  const float* x      = (const float*)d_in[0];
  const int*   mask   = (const int*)d_in[1];
  const float* W      = (const float*)d_in[2];
  const float* U      = (const float*)d_in[3];
  const float* bias   = (const float*)d_in[4];
  const float* gammas = (const float*)d_in[5];
  const float* betas  = (const float*)d_in[6];
  float* out = (float*)d_out;

  char* ws = (char*)d_ws;
  size_t off = 0;
  auto alloc = [&](size_t bytes) -> void* {
    void* p = ws + off;
    off += (bytes + 255) & ~(size_t)255;
    return p;
  };
  float*  h_seq = (float*) alloc((size_t)TT * BB * DD * 4);
  ushort* lnXW  = (ushort*)alloc((size_t)TT * BB * NPAD * 2);
  ushort* vbuf  = (ushort*)alloc((size_t)TT * BB * NPAD * 2);
  float*  fkbuf = (float*) alloc((size_t)TT * BB * 4);
  float*  hvbuf = (float*) alloc((size_t)TT * BB * 4);
  ushort* Wpk   = (ushort*)alloc((size_t)128 * NT * 16 * 8 * 2);
  ushort* Upk   = (ushort*)alloc((size_t)128 * NT * 16 * 8 * 2);
  uint*   Upk4  = (uint*)  alloc((size_t)64 * 512 * 4 * 4);
  float*  ucol  = (float*) alloc(512 * 4);

  int npk = 128 * NT * 16 * 8;
  prepack_B<<<dim3((npk + 255) / 256), dim3(256), 0, stream>>>(W, Wpk);
  prepack_B<<<dim3((npk + 255) / 256), dim3(256), 0, stream>>>(U, Upk);
  prepack_Uhi_pk<<<dim3((64 * 512 * 4 + 255) / 256), dim3(256), 0, stream>>>(U, Upk4, ucol);

  const float* g0 = gammas,      *g1 = gammas + NC;
  const float* be0 = betas,      *be1 = betas + NC;

  // layer 0: lnXW = LN(x @ W_lo)+b ; vbuf = x @ U_lo (raw)
  gemm_ln<<<dim3(256), dim3(1024), 0, stream>>>(x, 0, 16, Wpk, lnXW, 1, g0, be0, bias);
  gemm_ln<<<dim3(256), dim3(1024), 0, stream>>>(x, 0, 16, Upk, vbuf, 0, g0, be0, bias);
  rnn_layer<<<dim3(BB), dim3(1024), 0, stream>>>(0, x, h_seq, lnXW, vbuf, fkbuf, hvbuf,
                                                 Upk4, ucol, mask, g1, be1, bias, out);
  for (int d = 1; d < 4; d++){
    gemm_ln<<<dim3(256), dim3(1024), 0, stream>>>(h_seq, 1, 32, Wpk, lnXW, 1, g0, be0, bias);
    rnn_layer<<<dim3(BB), dim3(1024), 0, stream>>>(d, x, h_seq, lnXW, vbuf, fkbuf, hvbuf,
                                                   Upk4, ucol, mask, g1, be1, bias, out);
  }
}